// Round 15
// baseline (438.444 us; speedup 1.0000x reference)
//
#include <hip/hip_runtime.h>

typedef unsigned short u16;
typedef unsigned int   u32;
typedef __attribute__((ext_vector_type(8))) short bf16x8;
typedef __attribute__((ext_vector_type(4))) float f32x4;

#define DIMC   192
#define HH     56
#define WSZ    7
#define SSH    3
#define NTOK   49
#define NWIN_T 2048
#define HIDDEN 768
#define LTOT   3136
#define NTOKENS 100352

#define LDA    200    // u16 row stride, [64][<=192] tiles (400B rows)
#define LDSS   68     // f32 row stride of S
#define LDPU   136    // u16 view (2*LDSS): hi cols 0-63, lo cols 64-127
#define LDVT   72     // u16 row stride of V^T

// ws layout (u16 elems): bf16 W^T[N][K] (hi only; split-P keeps accuracy)
#define OFF_QKV 0                         // 576 cols * 192
#define OFF_PW  110592                    // + 192 * 192
#define OFF_W1  147456                    // + 768 * 192
#define OFF_W2  294912                    // + 192 * 768
#define WS_ELEMS 442368
#define WS_BYTES (WS_ELEMS * 2)
#define XATTN_ELEMS ((size_t)NWIN_T * NTOK * DIMC)
#define XATTN_BYTES (XATTN_ELEMS * 2)                    // 38.5 MB

#define MFMA(a,b,c) __builtin_amdgcn_mfma_f32_16x16x32_bf16((a),(b),(c),0,0,0)

__device__ __forceinline__ float bf2f(u16 u) {
    union { u32 i; float f; } v; v.i = ((u32)u) << 16; return v.f;
}
__device__ __forceinline__ u16 f2bf(float f) {
    union { float ff; u32 i; } v; v.ff = f;
    u32 x = v.i;
    return (u16)((x + 0x7FFFu + ((x >> 16) & 1u)) >> 16);  // RNE
}

// ---------------------------------------------------------------------------
// Prep: fp32 [K][N] weights -> bf16 W^T [N][K] in ws.
// ---------------------------------------------------------------------------
__global__ void cvt_weights(const float* __restrict__ qkv_w,
                            const float* __restrict__ proj_w,
                            const float* __restrict__ w1,
                            const float* __restrict__ w2,
                            u16* __restrict__ ws)
{
    const int idx = blockIdx.x * blockDim.x + threadIdx.x;
    const int stride = gridDim.x * blockDim.x;
    for (int i = idx; i < 110592; i += stride) {        // qkv [192][576]
        int k = i / 576, n = i - k * 576;
        ws[OFF_QKV + n * 192 + k] = f2bf(qkv_w[i]);
    }
    for (int i = idx; i < 36864; i += stride) {         // proj [192][192]
        int k = i / 192, n = i - k * 192;
        ws[OFF_PW + n * 192 + k] = f2bf(proj_w[i]);
    }
    for (int i = idx; i < 147456; i += stride) {        // w1 [192][768]
        int k = i / 768, n = i - k * 768;
        ws[OFF_W1 + n * 192 + k] = f2bf(w1[i]);
    }
    for (int i = idx; i < 147456; i += stride) {        // w2 [768][192]
        int k = i / 192, n = i - k * 192;
        ws[OFF_W2 + n * 768 + k] = f2bf(w2[i]);
    }
}

// ---------------------------------------------------------------------------
// P1: gather (shift -SSH) + LN1 -> s_A [64][192]; pad rows 49..63 zeroed.
// ---------------------------------------------------------------------------
__device__ __forceinline__ void ln1_gather(
    const float* __restrict__ x, const float* __restrict__ g1,
    const float* __restrict__ be1, u16* __restrict__ s_A,
    int b, int wi, int wj, int wv, int lane)
{
    for (int t = wv; t < 64; t += 4) {
        if (t < NTOK) {
            const int pi = t / 7, pj = t - pi * 7;
            const int si = (wi * WSZ + pi + SSH) % HH;
            const int sj = (wj * WSZ + pj + SSH) % HH;
            const float* src = x + ((size_t)b * LTOT + si * HH + sj) * DIMC;
            float v0 = src[lane], v1 = src[lane + 64], v2 = src[lane + 128];
            float s  = v0 + v1 + v2;
            float s2 = v0 * v0 + v1 * v1 + v2 * v2;
#pragma unroll
            for (int off = 32; off > 0; off >>= 1) {
                s  += __shfl_xor(s,  off);
                s2 += __shfl_xor(s2, off);
            }
            const float mu   = s * (1.f / 192.f);
            const float rstd = rsqrtf(s2 * (1.f / 192.f) - mu * mu + 1e-5f);
            s_A[t*LDA + lane      ] = f2bf((v0-mu)*rstd*g1[lane]     + be1[lane]);
            s_A[t*LDA + lane + 64 ] = f2bf((v1-mu)*rstd*g1[lane+64]  + be1[lane+64]);
            s_A[t*LDA + lane + 128] = f2bf((v2-mu)*rstd*g1[lane+128] + be1[lane+128]);
        } else {
            s_A[t*LDA + lane] = 0; s_A[t*LDA + lane + 64] = 0; s_A[t*LDA + lane + 128] = 0;
        }
    }
}

// ---------------------------------------------------------------------------
// attention: xn frags hoisted to regs; 3 QKV groups x 2 heads; MFMA QK^T,
// wave-parallel fp32 softmax, split hi/lo P MFMA PV. O ends in s_A.
// Caller may alias Sf/PU/Vt INTO s_A (xn is register-hoisted; O written only
// after last PV barrier).
// ---------------------------------------------------------------------------
__device__ __forceinline__ void attn_all(
    u16* __restrict__ s_A, u16* __restrict__ s_Q,
    float* Sf, u16* PU, u16* Vt,
    const u16* __restrict__ Wqkvt, const float* __restrict__ qkv_b,
    int tid, int wv, int ar, int ak, int rg0)
{
    const float scale = 0.1767766952966369f;   // 1/sqrt(32)
    f32x4 o[12];

    bf16x8 ax[4][6];
#pragma unroll
    for (int mt = 0; mt < 4; mt++)
#pragma unroll
        for (int kk = 0; kk < 6; kk++)
            ax[mt][kk] = *(const bf16x8*)&s_A[(mt*16 + ar)*LDA + kk*32 + ak];

#pragma unroll
    for (int G = 0; G < 3; G++) {
#pragma unroll
        for (int tl = 0; tl < 3; tl++) {
            const int tt = wv*3 + tl;
            const int section = tt >> 2, idxq = tt & 3;
            const int gcol = section*192 + G*64 + idxq*16 + ar;
            const int lcol = section*64 + idxq*16 + ar;
            const float bias = qkv_b[gcol];
            const u16* wc = Wqkvt + (size_t)gcol * 192;
            f32x4 acc[4];
#pragma unroll
            for (int mt = 0; mt < 4; mt++) acc[mt] = 0;
#pragma unroll
            for (int kk = 0; kk < 6; kk++) {
                bf16x8 bh = *(const bf16x8*)&wc[kk*32 + ak];
#pragma unroll
                for (int mt = 0; mt < 4; mt++)
                    acc[mt] = MFMA(ax[mt][kk], bh, acc[mt]);
            }
#pragma unroll
            for (int mt = 0; mt < 4; mt++)
#pragma unroll
                for (int rg = 0; rg < 4; rg++)
                    s_Q[(mt*16 + rg0 + rg)*LDA + lcol] = f2bf(acc[mt][rg] + bias);
        }
        __syncthreads();

#pragma unroll
        for (int HL = 0; HL < 2; HL++) {
            {
                bf16x8 bk = *(const bf16x8*)&s_Q[(wv*16 + ar)*LDA + 64 + HL*32 + ak];
#pragma unroll
                for (int mt = 0; mt < 4; mt++) {
                    bf16x8 aq = *(const bf16x8*)&s_Q[(mt*16 + ar)*LDA + HL*32 + ak];
                    f32x4 sa; sa = 0;
                    sa = MFMA(aq, bk, sa);
#pragma unroll
                    for (int rg = 0; rg < 4; rg++)
                        Sf[(mt*16 + rg0 + rg)*LDSS + wv*16 + ar] = sa[rg] * scale;
                }
            }
            __syncthreads();
            {
                const int row = tid >> 2, sub = tid & 3;
                if (row < NTOK) {
                    float e[16]; float m = -1e30f;
#pragma unroll
                    for (int i = 0; i < 16; i++) {
                        const int j = sub + 4*i;
                        e[i] = (j < NTOK) ? Sf[row*LDSS + j] : -1e30f;
                        m = fmaxf(m, e[i]);
                    }
                    m = fmaxf(m, __shfl_xor(m, 1));
                    m = fmaxf(m, __shfl_xor(m, 2));
                    float sum = 0.f;
#pragma unroll
                    for (int i = 0; i < 16; i++) { e[i] = __expf(e[i] - m); sum += e[i]; }
                    sum += __shfl_xor(sum, 1);
                    sum += __shfl_xor(sum, 2);
                    const float inv = 1.f / sum;
#pragma unroll
                    for (int i = 0; i < 16; i++) {
                        const int j = sub + 4*i;
                        const float p = e[i] * inv;   // 0 for j>=49 -> pad cols zero
                        const u16 hb = f2bf(p);
                        PU[row*LDPU + j] = hb;
                        PU[row*LDPU + 64 + j] = f2bf(p - bf2f(hb));
                    }
                }
                for (int i2 = tid; i2 < 2048; i2 += 256) {
                    const int d = i2 & 31, j = i2 >> 5;
                    Vt[d*LDVT + j] = (j < NTOK) ? s_Q[j*LDA + 128 + HL*32 + d] : (u16)0;
                }
            }
            __syncthreads();
            {
                const int dcol = (wv & 1)*16 + ar;
                const int mtb = (wv >> 1) << 1;
#pragma unroll
                for (int mi = 0; mi < 2; mi++) {
                    f32x4 accv; accv = 0;
#pragma unroll
                    for (int kk = 0; kk < 2; kk++) {
                        bf16x8 ph = *(const bf16x8*)&PU[((mtb+mi)*16 + ar)*LDPU + kk*32 + ak];
                        bf16x8 pl = *(const bf16x8*)&PU[((mtb+mi)*16 + ar)*LDPU + 64 + kk*32 + ak];
                        bf16x8 bv = *(const bf16x8*)&Vt[dcol*LDVT + kk*32 + ak];
                        accv = MFMA(ph, bv, accv);
                        accv = MFMA(pl, bv, accv);
                    }
                    o[(G*2 + HL)*2 + mi] = accv;
                }
            }
            __syncthreads();
        }
    }

    {
        const int mtb = (wv >> 1) << 1;
        const int cbase = (wv & 1)*16 + ar;
#pragma unroll
        for (int hp = 0; hp < 6; hp++) {
            const int col = hp*32 + cbase;
#pragma unroll
            for (int mi = 0; mi < 2; mi++)
#pragma unroll
                for (int rg = 0; rg < 4; rg++)
                    s_A[((mtb+mi)*16 + rg0 + rg)*LDA + col] = f2bf(o[hp*2 + mi][rg]);
        }
    }
    __syncthreads();
}

// ---------------------------------------------------------------------------
// K1: LN1 + QKV + attention + proj -> xattn. S/P/Vt alias into s_A ->
// 51.2 KB LDS (HW gives 3 blocks/CU); launch_bounds(256,2) keeps regalloc
// free (~128 VGPR, no spill). Proven ~137 us in r14. UNCHANGED.
// ---------------------------------------------------------------------------
__global__ __launch_bounds__(256, 2)
void swin_attn(const float* __restrict__ x,
               const float* __restrict__ qkv_b, const float* __restrict__ proj_b,
               const float* __restrict__ g1, const float* __restrict__ be1,
               const u16* __restrict__ wsw, u16* __restrict__ xattn)
{
    __shared__ __align__(16) u16 s_A[64 * LDA];                 // 25.6 KB
    __shared__ __align__(16) u16 s_Q[64 * LDA];                 // 25.6 KB

    float* const Sf = (float*)s_A;
    u16*  const PU  = s_A;
    u16*  const Vt  = s_A + 64 * LDPU;

    const int wid = blockIdx.x;
    const int b  = wid >> 6;
    const int wi = (wid >> 3) & 7;
    const int wj = wid & 7;
    const int tid  = threadIdx.x;
    const int wv   = tid >> 6;
    const int lane = tid & 63;
    const int ar   = lane & 15;
    const int ak   = (lane >> 4) << 3;
    const int rg0  = (lane >> 4) << 2;

    ln1_gather(x, g1, be1, s_A, b, wi, wj, wv, lane);
    __syncthreads();

    attn_all(s_A, s_Q, Sf, PU, Vt, wsw + OFF_QKV, qkv_b, tid, wv, ar, ak, rg0);

    // ---- proj: XW = O @ Wp + b -> global xattn (bf16) ----
    {
        const u16* Wpt = wsw + OFF_PW;
        bf16x8 ao[4][6];
#pragma unroll
        for (int mt = 0; mt < 4; mt++)
#pragma unroll
            for (int kk = 0; kk < 6; kk++)
                ao[mt][kk] = *(const bf16x8*)&s_A[(mt*16 + ar)*LDA + kk*32 + ak];
#pragma unroll
        for (int ntl = 0; ntl < 3; ntl++) {
            const int col = (wv*3 + ntl)*16 + ar;
            const float bias = proj_b[col];
            const u16* wc = Wpt + (size_t)col * 192;
            f32x4 acc[4];
#pragma unroll
            for (int mt = 0; mt < 4; mt++) acc[mt] = 0;
#pragma unroll
            for (int kk = 0; kk < 6; kk++) {
                bf16x8 bh = *(const bf16x8*)&wc[kk*32 + ak];
#pragma unroll
                for (int mt = 0; mt < 4; mt++)
                    acc[mt] = MFMA(ao[mt][kk], bh, acc[mt]);
            }
#pragma unroll
            for (int mt = 0; mt < 4; mt++)
#pragma unroll
                for (int rg = 0; rg < 4; rg++) {
                    const int row = mt*16 + rg0 + rg;
                    if (row < NTOK)
                        xattn[((size_t)wid * NTOK + row) * DIMC + col] =
                            f2bf(acc[mt][rg] + bias);
                }
        }
    }
}

// ---------------------------------------------------------------------------
// K2: LN2 + MLP + residual — r9 structure (erff gelu) + W2 REGISTER PREFETCH:
// GEMM2(cc)'s 18 weight loads issue at the top of GEMM1(cc); the barrier's
// vmcnt drain completes them, so GEMM2 runs pure LDS+MFMA (no global stalls).
// + s_dest table kills per-output div/mod chains. 51.2 KB LDS, (256,3).
// ---------------------------------------------------------------------------
__global__ __launch_bounds__(256, 3)
void swin_mlp(const u16* __restrict__ xattn,
              const float* __restrict__ g2, const float* __restrict__ be2,
              const float* __restrict__ b1f, const float* __restrict__ b2f,
              const u16* __restrict__ wsw, float* __restrict__ out)
{
    __shared__ __align__(16) u16 s_X[64 * LDA];    // 25.6 KB (xln)
    __shared__ __align__(16) u16 s_H[64 * LDA];    // 25.6 KB (h 192-col chunk)
    __shared__ u32 s_dest[64];                     // per-row out base offsets

    const int tid  = threadIdx.x;
    const int wv   = tid >> 6;
    const int lane = tid & 63;
    const int ar   = lane & 15;
    const int ak   = (lane >> 4) << 3;
    const int rg0  = (lane >> 4) << 2;
    const int base = blockIdx.x * 64;
    const u16* W1t = wsw + OFF_W1;
    const u16* W2t = wsw + OFF_W2;

    // ---- LN2 over 64 token rows + dest-table fill ----
    for (int t = wv; t < 64; t += 4) {
        const u16* src = xattn + (size_t)(base + t) * DIMC;
        float v0 = bf2f(src[lane]);
        float v1 = bf2f(src[lane + 64]);
        float v2 = bf2f(src[lane + 128]);
        float s  = v0 + v1 + v2;
        float s2 = v0*v0 + v1*v1 + v2*v2;
#pragma unroll
        for (int off = 32; off > 0; off >>= 1) {
            s  += __shfl_xor(s,  off);
            s2 += __shfl_xor(s2, off);
        }
        const float mu   = s * (1.f / 192.f);
        const float rstd = rsqrtf(s2 * (1.f / 192.f) - mu * mu + 1e-5f);
        s_X[t*LDA + lane      ] = f2bf((v0-mu)*rstd*g2[lane]     + be2[lane]);
        s_X[t*LDA + lane + 64 ] = f2bf((v1-mu)*rstd*g2[lane+64]  + be2[lane+64]);
        s_X[t*LDA + lane + 128] = f2bf((v2-mu)*rstd*g2[lane+128] + be2[lane+128]);
    }
    if (tid < 64) {
        const int grow = base + tid;
        const int w = grow / 49, t = grow - w * 49;
        const int bb = w >> 6, wi = (w >> 3) & 7, wj = w & 7;
        const int pi = t / 7, pj = t - pi * 7;
        const int di = (wi * WSZ + pi + SSH) % HH;
        const int dj = (wj * WSZ + pj + SSH) % HH;
        s_dest[tid] = (u32)((bb * LTOT + di * HH + dj) * DIMC);
    }
    __syncthreads();

    // ---- MLP: 4 hidden-chunks of 192; accO in regs; W2 reg-prefetch ----
    f32x4 accO[3][4];
#pragma unroll
    for (int i = 0; i < 3; i++)
#pragma unroll
        for (int m = 0; m < 4; m++) accO[i][m] = 0;

    for (int cc = 0; cc < 4; cc++) {
        // -- prefetch GEMM2(cc)'s weights (static-indexed regs; in flight
        //    through GEMM1; completed by the barrier's vmcnt drain) --
        bf16x8 w2p[3][6];
#pragma unroll
        for (int ntl = 0; ntl < 3; ntl++) {
            const int col = (wv*3 + ntl)*16 + ar;
#pragma unroll
            for (int kk = 0; kk < 6; kk++)
                w2p[ntl][kk] = *(const bf16x8*)&W2t[(size_t)col * 768 + cc*192 + kk*32 + ak];
        }
        // -- GEMM1 chunk (kk-outer, a4 reuse, r9-proven) --
        {
            f32x4 acc1[3][4];
#pragma unroll
            for (int i = 0; i < 3; i++)
#pragma unroll
                for (int m = 0; m < 4; m++) acc1[i][m] = 0;
#pragma unroll
            for (int kk = 0; kk < 6; kk++) {
                bf16x8 a4[4];
#pragma unroll
                for (int mt = 0; mt < 4; mt++)
                    a4[mt] = *(const bf16x8*)&s_X[(mt*16 + ar)*LDA + kk*32 + ak];
#pragma unroll
                for (int ntl = 0; ntl < 3; ntl++) {
                    const int ngl = cc*192 + (wv*3 + ntl)*16 + ar;
                    bf16x8 w = *(const bf16x8*)&W1t[(size_t)ngl * 192 + kk*32 + ak];
#pragma unroll
                    for (int mt = 0; mt < 4; mt++)
                        acc1[ntl][mt] = MFMA(a4[mt], w, acc1[ntl][mt]);
                }
            }
#pragma unroll
            for (int ntl = 0; ntl < 3; ntl++) {
                const int ncol = (wv*3 + ntl)*16 + ar;
                const float bias = b1f[cc*192 + ncol];
#pragma unroll
                for (int mt = 0; mt < 4; mt++)
#pragma unroll
                    for (int rg = 0; rg < 4; rg++) {
                        const float z = acc1[ntl][mt][rg] + bias;
                        const float ge = 0.5f * z * (1.f + erff(z * 0.70710678118654752f));
                        s_H[(mt*16 + rg0 + rg)*LDA + ncol] = f2bf(ge);
                    }
            }
        }
        __syncthreads();
        // -- GEMM2 partial: pure LDS + MFMA (weights already in w2p) --
        {
#pragma unroll
            for (int kk = 0; kk < 6; kk++) {
                bf16x8 a4[4];
#pragma unroll
                for (int mt = 0; mt < 4; mt++)
                    a4[mt] = *(const bf16x8*)&s_H[(mt*16 + ar)*LDA + kk*32 + ak];
#pragma unroll
                for (int ntl = 0; ntl < 3; ntl++)
#pragma unroll
                    for (int mt = 0; mt < 4; mt++)
                        accO[ntl][mt] = MFMA(a4[mt], w2p[ntl][kk], accO[ntl][mt]);
            }
        }
        __syncthreads();
    }

    // ---- epilogue: out = accO + b2 + residual, via dest table ----
#pragma unroll
    for (int ntl = 0; ntl < 3; ntl++) {
        const int col = (wv*3 + ntl)*16 + ar;
        const float bias = b2f[col];
#pragma unroll
        for (int mt = 0; mt < 4; mt++)
#pragma unroll
            for (int rg = 0; rg < 4; rg++) {
                const int row = mt*16 + rg0 + rg;            // block-local
                const size_t grow = (size_t)base + row;
                out[(size_t)s_dest[row] + col] =
                    accO[ntl][mt][rg] + bias + bf2f(xattn[grow * DIMC + col]);
            }
    }
}

// ---------------------------------------------------------------------------
// Fallback: monolithic fused kernel (2 blocks/CU), if ws too small for xattn.
// ---------------------------------------------------------------------------
__global__ __launch_bounds__(256, 2)
void swin_mono(const float* __restrict__ x,
               const float* __restrict__ qkv_b, const float* __restrict__ proj_b,
               const float* __restrict__ g1, const float* __restrict__ be1,
               const float* __restrict__ g2, const float* __restrict__ be2,
               const float* __restrict__ b1f, const float* __restrict__ b2f,
               const u16* __restrict__ wsw, float* __restrict__ out)
{
    __shared__ __align__(16) u16 s_A[64 * LDA];
    __shared__ __align__(16) u16 s_Q[64 * LDA];
    __shared__ __align__(16) u16 s_R3[64 * LDA];

    float* const Sf  = (float*)s_R3;
    u16*  const PU   = s_R3;
    u16*  const Vt   = s_R3 + 64 * LDPU;
    u16*  const s_H  = s_R3;
    u16*  const s_XW = s_Q;

    const int wid = blockIdx.x;
    const int b  = wid >> 6;
    const int wi = (wid >> 3) & 7;
    const int wj = wid & 7;
    const int tid  = threadIdx.x;
    const int wv   = tid >> 6;
    const int lane = tid & 63;
    const int ar   = lane & 15;
    const int ak   = (lane >> 4) << 3;
    const int rg0  = (lane >> 4) << 2;

    const u16* Wpt = wsw + OFF_PW;
    const u16* W1t = wsw + OFF_W1;
    const u16* W2t = wsw + OFF_W2;

    ln1_gather(x, g1, be1, s_A, b, wi, wj, wv, lane);
    __syncthreads();

    attn_all(s_A, s_Q, Sf, PU, Vt, wsw + OFF_QKV, qkv_b, tid, wv, ar, ak, rg0);

    {
        bf16x8 ao[4][6];
#pragma unroll
        for (int mt = 0; mt < 4; mt++)
#pragma unroll
            for (int kk = 0; kk < 6; kk++)
                ao[mt][kk] = *(const bf16x8*)&s_A[(mt*16 + ar)*LDA + kk*32 + ak];
#pragma unroll
        for (int ntl = 0; ntl < 3; ntl++) {
            const int col = (wv*3 + ntl)*16 + ar;
            const float bias = proj_b[col];
            const u16* wc = Wpt + (size_t)col * 192;
            f32x4 acc[4];
#pragma unroll
            for (int mt = 0; mt < 4; mt++) acc[mt] = 0;
#pragma unroll
            for (int kk = 0; kk < 6; kk++) {
                bf16x8 bh = *(const bf16x8*)&wc[kk*32 + ak];
#pragma unroll
                for (int mt = 0; mt < 4; mt++)
                    acc[mt] = MFMA(ao[mt][kk], bh, acc[mt]);
            }
#pragma unroll
            for (int mt = 0; mt < 4; mt++)
#pragma unroll
                for (int rg = 0; rg < 4; rg++)
                    s_XW[(mt*16 + rg0 + rg)*LDA + col] = f2bf(acc[mt][rg] + bias);
        }
    }
    __syncthreads();

    for (int t = wv; t < NTOK; t += 4) {
        float v0 = bf2f(s_XW[t*LDA + lane      ]);
        float v1 = bf2f(s_XW[t*LDA + lane + 64 ]);
        float v2 = bf2f(s_XW[t*LDA + lane + 128]);
        float s  = v0 + v1 + v2;
        float s2 = v0*v0 + v1*v1 + v2*v2;
#pragma unroll
        for (int off = 32; off > 0; off >>= 1) {
            s  += __shfl_xor(s,  off);
            s2 += __shfl_xor(s2, off);
        }
        const float mu   = s * (1.f / 192.f);
        const float rstd = rsqrtf(s2 * (1.f / 192.f) - mu * mu + 1e-5f);
        s_A[t*LDA + lane      ] = f2bf((v0-mu)*rstd*g2[lane]     + be2[lane]);
        s_A[t*LDA + lane + 64 ] = f2bf((v1-mu)*rstd*g2[lane+64]  + be2[lane+64]);
        s_A[t*LDA + lane + 128] = f2bf((v2-mu)*rstd*g2[lane+128] + be2[lane+128]);
    }
    __syncthreads();

    f32x4 accO[3][4];
#pragma unroll
    for (int i = 0; i < 3; i++)
#pragma unroll
        for (int m = 0; m < 4; m++) accO[i][m] = 0;

    for (int cc = 0; cc < 4; cc++) {
        {
            f32x4 acc1[3][4];
#pragma unroll
            for (int i = 0; i < 3; i++)
#pragma unroll
                for (int m = 0; m < 4; m++) acc1[i][m] = 0;
#pragma unroll
            for (int kk = 0; kk < 6; kk++) {
                bf16x8 a4[4];
#pragma unroll
                for (int mt = 0; mt < 4; mt++)
                    a4[mt] = *(const bf16x8*)&s_A[(mt*16 + ar)*LDA + kk*32 + ak];
#pragma unroll
                for (int ntl = 0; ntl < 3; ntl++) {
                    const int ngl = cc*192 + (wv*3 + ntl)*16 + ar;
                    bf16x8 w = *(const bf16x8*)&W1t[(size_t)ngl * 192 + kk*32 + ak];
#pragma unroll
                    for (int mt = 0; mt < 4; mt++)
                        acc1[ntl][mt] = MFMA(a4[mt], w, acc1[ntl][mt]);
                }
            }
#pragma unroll
            for (int ntl = 0; ntl < 3; ntl++) {
                const int ncol = (wv*3 + ntl)*16 + ar;
                const float bias = b1f[cc*192 + ncol];
#pragma unroll
                for (int mt = 0; mt < 4; mt++)
#pragma unroll
                    for (int rg = 0; rg < 4; rg++) {
                        const float z = acc1[ntl][mt][rg] + bias;
                        const float ge = 0.5f * z * (1.f + erff(z * 0.70710678118654752f));
                        s_H[(mt*16 + rg0 + rg)*LDA + ncol] = f2bf(ge);
                    }
            }
        }
        __syncthreads();
        {
#pragma unroll
            for (int kk = 0; kk < 6; kk++) {
                bf16x8 a4[4];
#pragma unroll
                for (int mt = 0; mt < 4; mt++)
                    a4[mt] = *(const bf16x8*)&s_H[(mt*16 + ar)*LDA + kk*32 + ak];
#pragma unroll
                for (int ntl = 0; ntl < 3; ntl++) {
                    const int col = (wv*3 + ntl)*16 + ar;
                    bf16x8 w = *(const bf16x8*)&W2t[(size_t)col * 768 + cc*192 + kk*32 + ak];
#pragma unroll
                    for (int mt = 0; mt < 4; mt++)
                        accO[ntl][mt] = MFMA(a4[mt], w, accO[ntl][mt]);
                }
            }
        }
        __syncthreads();
    }

#pragma unroll
    for (int ntl = 0; ntl < 3; ntl++) {
        const int col = (wv*3 + ntl)*16 + ar;
        const float bias = b2f[col];
#pragma unroll
        for (int mt = 0; mt < 4; mt++)
#pragma unroll
            for (int rg = 0; rg < 4; rg++) {
                const int row = mt*16 + rg0 + rg;
                if (row < NTOK) {
                    const int pi = row / 7, pj = row - pi * 7;
                    const int di = (wi * WSZ + pi + SSH) % HH;
                    const int dj = (wj * WSZ + pj + SSH) % HH;
                    out[((size_t)b * LTOT + di * HH + dj) * DIMC + col] =
                        accO[ntl][mt][rg] + bias + bf2f(s_XW[row*LDA + col]);
                }
            }
    }
}

extern "C" void kernel_launch(void* const* d_in, const int* in_sizes, int n_in,
                              void* d_out, int out_size, void* d_ws, size_t ws_size,
                              hipStream_t stream)
{
    const float* x      = (const float*)d_in[0];
    const float* qkv_w  = (const float*)d_in[1];
    const float* qkv_b  = (const float*)d_in[2];
    const float* proj_w = (const float*)d_in[3];
    const float* proj_b = (const float*)d_in[4];
    const float* g1     = (const float*)d_in[5];
    const float* be1    = (const float*)d_in[6];
    const float* g2     = (const float*)d_in[7];
    const float* be2    = (const float*)d_in[8];
    const float* w1     = (const float*)d_in[9];
    const float* b1     = (const float*)d_in[10];
    const float* w2     = (const float*)d_in[11];
    const float* b2     = (const float*)d_in[12];
    float* out = (float*)d_out;

    cvt_weights<<<256, 256, 0, stream>>>(qkv_w, proj_w, w1, w2, (u16*)d_ws);

    if (ws_size >= (size_t)WS_BYTES + XATTN_BYTES) {
        u16* xattn = (u16*)d_ws + WS_ELEMS;
        swin_attn<<<NWIN_T, 256, 0, stream>>>(x, qkv_b, proj_b, g1, be1,
                                              (const u16*)d_ws, xattn);
        swin_mlp<<<NTOKENS/64, 256, 0, stream>>>(xattn, g2, be2, b1, b2,
                                                 (const u16*)d_ws, out);
    } else {
        swin_mono<<<NWIN_T, 256, 0, stream>>>(x, qkv_b, proj_b, g1, be1, g2, be2,
                                              b1, b2, (const u16*)d_ws, out);
    }
}

// Round 16
// 348.238 us; speedup vs baseline: 1.2590x; 1.2590x over previous
//
#include <hip/hip_runtime.h>

typedef unsigned short u16;
typedef unsigned int   u32;
typedef __attribute__((ext_vector_type(8))) short bf16x8;
typedef __attribute__((ext_vector_type(4))) float f32x4;

#define DIMC   192
#define HH     56
#define WSZ    7
#define SSH    3
#define NTOK   49
#define NWIN_T 2048
#define HIDDEN 768
#define LTOT   3136
#define NTOKENS 100352

#define LDA    200    // u16 row stride, [64][<=192] tiles (400B rows)
#define LDSS   68     // f32 row stride of S
#define LDPU   136    // u16 view (2*LDSS): hi cols 0-63, lo cols 64-127
#define LDVT   72     // u16 row stride of V^T

// ws layout (u16 elems): bf16 W^T[N][K] (hi only; split-P keeps accuracy)
#define OFF_QKV 0                         // 576 cols * 192
#define OFF_PW  110592                    // + 192 * 192
#define OFF_W1  147456                    // + 768 * 192
#define OFF_W2  294912                    // + 192 * 768
#define WS_ELEMS 442368
#define WS_BYTES (WS_ELEMS * 2)
#define XATTN_ELEMS ((size_t)NWIN_T * NTOK * DIMC)
#define XATTN_BYTES (XATTN_ELEMS * 2)                    // 38.5 MB

#define MFMA(a,b,c) __builtin_amdgcn_mfma_f32_16x16x32_bf16((a),(b),(c),0,0,0)

__device__ __forceinline__ float bf2f(u16 u) {
    union { u32 i; float f; } v; v.i = ((u32)u) << 16; return v.f;
}
__device__ __forceinline__ u16 f2bf(float f) {
    union { float ff; u32 i; } v; v.ff = f;
    u32 x = v.i;
    return (u16)((x + 0x7FFFu + ((x >> 16) & 1u)) >> 16);  // RNE
}

// ---------------------------------------------------------------------------
// Prep: fp32 [K][N] weights -> bf16 W^T [N][K] in ws.
// ---------------------------------------------------------------------------
__global__ void cvt_weights(const float* __restrict__ qkv_w,
                            const float* __restrict__ proj_w,
                            const float* __restrict__ w1,
                            const float* __restrict__ w2,
                            u16* __restrict__ ws)
{
    const int idx = blockIdx.x * blockDim.x + threadIdx.x;
    const int stride = gridDim.x * blockDim.x;
    for (int i = idx; i < 110592; i += stride) {        // qkv [192][576]
        int k = i / 576, n = i - k * 576;
        ws[OFF_QKV + n * 192 + k] = f2bf(qkv_w[i]);
    }
    for (int i = idx; i < 36864; i += stride) {         // proj [192][192]
        int k = i / 192, n = i - k * 192;
        ws[OFF_PW + n * 192 + k] = f2bf(proj_w[i]);
    }
    for (int i = idx; i < 147456; i += stride) {        // w1 [192][768]
        int k = i / 768, n = i - k * 768;
        ws[OFF_W1 + n * 192 + k] = f2bf(w1[i]);
    }
    for (int i = idx; i < 147456; i += stride) {        // w2 [768][192]
        int k = i / 192, n = i - k * 192;
        ws[OFF_W2 + n * 768 + k] = f2bf(w2[i]);
    }
}

// ---------------------------------------------------------------------------
// P1: gather (shift -SSH) + LN1 -> s_A [64][192]; pad rows 49..63 zeroed.
// ---------------------------------------------------------------------------
__device__ __forceinline__ void ln1_gather(
    const float* __restrict__ x, const float* __restrict__ g1,
    const float* __restrict__ be1, u16* __restrict__ s_A,
    int b, int wi, int wj, int wv, int lane)
{
    for (int t = wv; t < 64; t += 4) {
        if (t < NTOK) {
            const int pi = t / 7, pj = t - pi * 7;
            const int si = (wi * WSZ + pi + SSH) % HH;
            const int sj = (wj * WSZ + pj + SSH) % HH;
            const float* src = x + ((size_t)b * LTOT + si * HH + sj) * DIMC;
            float v0 = src[lane], v1 = src[lane + 64], v2 = src[lane + 128];
            float s  = v0 + v1 + v2;
            float s2 = v0 * v0 + v1 * v1 + v2 * v2;
#pragma unroll
            for (int off = 32; off > 0; off >>= 1) {
                s  += __shfl_xor(s,  off);
                s2 += __shfl_xor(s2, off);
            }
            const float mu   = s * (1.f / 192.f);
            const float rstd = rsqrtf(s2 * (1.f / 192.f) - mu * mu + 1e-5f);
            s_A[t*LDA + lane      ] = f2bf((v0-mu)*rstd*g1[lane]     + be1[lane]);
            s_A[t*LDA + lane + 64 ] = f2bf((v1-mu)*rstd*g1[lane+64]  + be1[lane+64]);
            s_A[t*LDA + lane + 128] = f2bf((v2-mu)*rstd*g1[lane+128] + be1[lane+128]);
        } else {
            s_A[t*LDA + lane] = 0; s_A[t*LDA + lane + 64] = 0; s_A[t*LDA + lane + 128] = 0;
        }
    }
}

// ---------------------------------------------------------------------------
// attention: xn frags hoisted to regs; 3 QKV groups x 2 heads; MFMA QK^T,
// wave-parallel fp32 softmax, split hi/lo P MFMA PV. O ends in s_A.
// Caller may alias Sf/PU/Vt INTO s_A (xn is register-hoisted; O written only
// after last PV barrier).
// ---------------------------------------------------------------------------
__device__ __forceinline__ void attn_all(
    u16* __restrict__ s_A, u16* __restrict__ s_Q,
    float* Sf, u16* PU, u16* Vt,
    const u16* __restrict__ Wqkvt, const float* __restrict__ qkv_b,
    int tid, int wv, int ar, int ak, int rg0)
{
    const float scale = 0.1767766952966369f;   // 1/sqrt(32)
    f32x4 o[12];

    bf16x8 ax[4][6];
#pragma unroll
    for (int mt = 0; mt < 4; mt++)
#pragma unroll
        for (int kk = 0; kk < 6; kk++)
            ax[mt][kk] = *(const bf16x8*)&s_A[(mt*16 + ar)*LDA + kk*32 + ak];

#pragma unroll
    for (int G = 0; G < 3; G++) {
#pragma unroll
        for (int tl = 0; tl < 3; tl++) {
            const int tt = wv*3 + tl;
            const int section = tt >> 2, idxq = tt & 3;
            const int gcol = section*192 + G*64 + idxq*16 + ar;
            const int lcol = section*64 + idxq*16 + ar;
            const float bias = qkv_b[gcol];
            const u16* wc = Wqkvt + (size_t)gcol * 192;
            f32x4 acc[4];
#pragma unroll
            for (int mt = 0; mt < 4; mt++) acc[mt] = 0;
#pragma unroll
            for (int kk = 0; kk < 6; kk++) {
                bf16x8 bh = *(const bf16x8*)&wc[kk*32 + ak];
#pragma unroll
                for (int mt = 0; mt < 4; mt++)
                    acc[mt] = MFMA(ax[mt][kk], bh, acc[mt]);
            }
#pragma unroll
            for (int mt = 0; mt < 4; mt++)
#pragma unroll
                for (int rg = 0; rg < 4; rg++)
                    s_Q[(mt*16 + rg0 + rg)*LDA + lcol] = f2bf(acc[mt][rg] + bias);
        }
        __syncthreads();

#pragma unroll
        for (int HL = 0; HL < 2; HL++) {
            {
                bf16x8 bk = *(const bf16x8*)&s_Q[(wv*16 + ar)*LDA + 64 + HL*32 + ak];
#pragma unroll
                for (int mt = 0; mt < 4; mt++) {
                    bf16x8 aq = *(const bf16x8*)&s_Q[(mt*16 + ar)*LDA + HL*32 + ak];
                    f32x4 sa; sa = 0;
                    sa = MFMA(aq, bk, sa);
#pragma unroll
                    for (int rg = 0; rg < 4; rg++)
                        Sf[(mt*16 + rg0 + rg)*LDSS + wv*16 + ar] = sa[rg] * scale;
                }
            }
            __syncthreads();
            {
                const int row = tid >> 2, sub = tid & 3;
                if (row < NTOK) {
                    float e[16]; float m = -1e30f;
#pragma unroll
                    for (int i = 0; i < 16; i++) {
                        const int j = sub + 4*i;
                        e[i] = (j < NTOK) ? Sf[row*LDSS + j] : -1e30f;
                        m = fmaxf(m, e[i]);
                    }
                    m = fmaxf(m, __shfl_xor(m, 1));
                    m = fmaxf(m, __shfl_xor(m, 2));
                    float sum = 0.f;
#pragma unroll
                    for (int i = 0; i < 16; i++) { e[i] = __expf(e[i] - m); sum += e[i]; }
                    sum += __shfl_xor(sum, 1);
                    sum += __shfl_xor(sum, 2);
                    const float inv = 1.f / sum;
#pragma unroll
                    for (int i = 0; i < 16; i++) {
                        const int j = sub + 4*i;
                        const float p = e[i] * inv;   // 0 for j>=49 -> pad cols zero
                        const u16 hb = f2bf(p);
                        PU[row*LDPU + j] = hb;
                        PU[row*LDPU + 64 + j] = f2bf(p - bf2f(hb));
                    }
                }
                for (int i2 = tid; i2 < 2048; i2 += 256) {
                    const int d = i2 & 31, j = i2 >> 5;
                    Vt[d*LDVT + j] = (j < NTOK) ? s_Q[j*LDA + 128 + HL*32 + d] : (u16)0;
                }
            }
            __syncthreads();
            {
                const int dcol = (wv & 1)*16 + ar;
                const int mtb = (wv >> 1) << 1;
#pragma unroll
                for (int mi = 0; mi < 2; mi++) {
                    f32x4 accv; accv = 0;
#pragma unroll
                    for (int kk = 0; kk < 2; kk++) {
                        bf16x8 ph = *(const bf16x8*)&PU[((mtb+mi)*16 + ar)*LDPU + kk*32 + ak];
                        bf16x8 pl = *(const bf16x8*)&PU[((mtb+mi)*16 + ar)*LDPU + 64 + kk*32 + ak];
                        bf16x8 bv = *(const bf16x8*)&Vt[dcol*LDVT + kk*32 + ak];
                        accv = MFMA(ph, bv, accv);
                        accv = MFMA(pl, bv, accv);
                    }
                    o[(G*2 + HL)*2 + mi] = accv;
                }
            }
            __syncthreads();
        }
    }

    {
        const int mtb = (wv >> 1) << 1;
        const int cbase = (wv & 1)*16 + ar;
#pragma unroll
        for (int hp = 0; hp < 6; hp++) {
            const int col = hp*32 + cbase;
#pragma unroll
            for (int mi = 0; mi < 2; mi++)
#pragma unroll
                for (int rg = 0; rg < 4; rg++)
                    s_A[((mtb+mi)*16 + rg0 + rg)*LDA + col] = f2bf(o[hp*2 + mi][rg]);
        }
    }
    __syncthreads();
}

// ---------------------------------------------------------------------------
// K1: LN1 + QKV + attention + proj -> xattn. S/P/Vt alias into s_A ->
// 51.2 KB LDS (HW gives 3 blocks/CU); launch_bounds(256,2) keeps regalloc
// free (~128 VGPR, no spill). Direct-measured ~137 us in r14. UNCHANGED.
// ---------------------------------------------------------------------------
__global__ __launch_bounds__(256, 2)
void swin_attn(const float* __restrict__ x,
               const float* __restrict__ qkv_b, const float* __restrict__ proj_b,
               const float* __restrict__ g1, const float* __restrict__ be1,
               const u16* __restrict__ wsw, u16* __restrict__ xattn)
{
    __shared__ __align__(16) u16 s_A[64 * LDA];                 // 25.6 KB
    __shared__ __align__(16) u16 s_Q[64 * LDA];                 // 25.6 KB

    float* const Sf = (float*)s_A;
    u16*  const PU  = s_A;
    u16*  const Vt  = s_A + 64 * LDPU;

    const int wid = blockIdx.x;
    const int b  = wid >> 6;
    const int wi = (wid >> 3) & 7;
    const int wj = wid & 7;
    const int tid  = threadIdx.x;
    const int wv   = tid >> 6;
    const int lane = tid & 63;
    const int ar   = lane & 15;
    const int ak   = (lane >> 4) << 3;
    const int rg0  = (lane >> 4) << 2;

    ln1_gather(x, g1, be1, s_A, b, wi, wj, wv, lane);
    __syncthreads();

    attn_all(s_A, s_Q, Sf, PU, Vt, wsw + OFF_QKV, qkv_b, tid, wv, ar, ak, rg0);

    // ---- proj: XW = O @ Wp + b -> global xattn (bf16) ----
    {
        const u16* Wpt = wsw + OFF_PW;
        bf16x8 ao[4][6];
#pragma unroll
        for (int mt = 0; mt < 4; mt++)
#pragma unroll
            for (int kk = 0; kk < 6; kk++)
                ao[mt][kk] = *(const bf16x8*)&s_A[(mt*16 + ar)*LDA + kk*32 + ak];
#pragma unroll
        for (int ntl = 0; ntl < 3; ntl++) {
            const int col = (wv*3 + ntl)*16 + ar;
            const float bias = proj_b[col];
            const u16* wc = Wpt + (size_t)col * 192;
            f32x4 acc[4];
#pragma unroll
            for (int mt = 0; mt < 4; mt++) acc[mt] = 0;
#pragma unroll
            for (int kk = 0; kk < 6; kk++) {
                bf16x8 bh = *(const bf16x8*)&wc[kk*32 + ak];
#pragma unroll
                for (int mt = 0; mt < 4; mt++)
                    acc[mt] = MFMA(ao[mt][kk], bh, acc[mt]);
            }
#pragma unroll
            for (int mt = 0; mt < 4; mt++)
#pragma unroll
                for (int rg = 0; rg < 4; rg++) {
                    const int row = mt*16 + rg0 + rg;
                    if (row < NTOK)
                        xattn[((size_t)wid * NTOK + row) * DIMC + col] =
                            f2bf(acc[mt][rg] + bias);
                }
        }
    }
}

// ---------------------------------------------------------------------------
// K2: LN2 + MLP + residual — r9-EXACT kernel (direct-measured 206 us;
// 5 structural variants all regressed: spill/traffic/LDS-occupancy).
// erff gelu, kk-outer a4 reuse, 51.2 KB LDS, (256,3), VGPR 80 no spill.
// ---------------------------------------------------------------------------
__global__ __launch_bounds__(256, 3)
void swin_mlp(const u16* __restrict__ xattn,
              const float* __restrict__ g2, const float* __restrict__ be2,
              const float* __restrict__ b1f, const float* __restrict__ b2f,
              const u16* __restrict__ wsw, float* __restrict__ out)
{
    __shared__ __align__(16) u16 s_X[64 * LDA];    // 25.6 KB (xln)
    __shared__ __align__(16) u16 s_H[64 * LDA];    // 25.6 KB (h 192-col chunk)

    const int tid  = threadIdx.x;
    const int wv   = tid >> 6;
    const int lane = tid & 63;
    const int ar   = lane & 15;
    const int ak   = (lane >> 4) << 3;
    const int rg0  = (lane >> 4) << 2;
    const int base = blockIdx.x * 64;
    const u16* W1t = wsw + OFF_W1;
    const u16* W2t = wsw + OFF_W2;

    // ---- LN2 over 64 token rows ----
    for (int t = wv; t < 64; t += 4) {
        const u16* src = xattn + (size_t)(base + t) * DIMC;
        float v0 = bf2f(src[lane]);
        float v1 = bf2f(src[lane + 64]);
        float v2 = bf2f(src[lane + 128]);
        float s  = v0 + v1 + v2;
        float s2 = v0*v0 + v1*v1 + v2*v2;
#pragma unroll
        for (int off = 32; off > 0; off >>= 1) {
            s  += __shfl_xor(s,  off);
            s2 += __shfl_xor(s2, off);
        }
        const float mu   = s * (1.f / 192.f);
        const float rstd = rsqrtf(s2 * (1.f / 192.f) - mu * mu + 1e-5f);
        s_X[t*LDA + lane      ] = f2bf((v0-mu)*rstd*g2[lane]     + be2[lane]);
        s_X[t*LDA + lane + 64 ] = f2bf((v1-mu)*rstd*g2[lane+64]  + be2[lane+64]);
        s_X[t*LDA + lane + 128] = f2bf((v2-mu)*rstd*g2[lane+128] + be2[lane+128]);
    }
    __syncthreads();

    // ---- MLP: 4 hidden-chunks of 192; accO in regs across chunks ----
    f32x4 accO[3][4];
#pragma unroll
    for (int i = 0; i < 3; i++)
#pragma unroll
        for (int m = 0; m < 4; m++) accO[i][m] = 0;

    for (int cc = 0; cc < 4; cc++) {
        // MLP1 chunk: 3 col-tiles per wave, A-frag reused across tiles per kk
        {
            f32x4 acc1[3][4];
#pragma unroll
            for (int i = 0; i < 3; i++)
#pragma unroll
                for (int m = 0; m < 4; m++) acc1[i][m] = 0;
#pragma unroll
            for (int kk = 0; kk < 6; kk++) {
                bf16x8 a4[4];
#pragma unroll
                for (int mt = 0; mt < 4; mt++)
                    a4[mt] = *(const bf16x8*)&s_X[(mt*16 + ar)*LDA + kk*32 + ak];
#pragma unroll
                for (int ntl = 0; ntl < 3; ntl++) {
                    const int ngl = cc*192 + (wv*3 + ntl)*16 + ar;
                    bf16x8 w = *(const bf16x8*)&W1t[(size_t)ngl * 192 + kk*32 + ak];
#pragma unroll
                    for (int mt = 0; mt < 4; mt++)
                        acc1[ntl][mt] = MFMA(a4[mt], w, acc1[ntl][mt]);
                }
            }
#pragma unroll
            for (int ntl = 0; ntl < 3; ntl++) {
                const int ncol = (wv*3 + ntl)*16 + ar;
                const float bias = b1f[cc*192 + ncol];
#pragma unroll
                for (int mt = 0; mt < 4; mt++)
#pragma unroll
                    for (int rg = 0; rg < 4; rg++) {
                        const float z = acc1[ntl][mt][rg] + bias;
                        const float ge = 0.5f * z * (1.f + erff(z * 0.70710678118654752f));
                        s_H[(mt*16 + rg0 + rg)*LDA + ncol] = f2bf(ge);
                    }
            }
        }
        __syncthreads();
        // MLP2 partial over this 192-wide K chunk (kk-outer, a4 reuse)
        {
#pragma unroll
            for (int kk = 0; kk < 6; kk++) {
                bf16x8 a4[4];
#pragma unroll
                for (int mt = 0; mt < 4; mt++)
                    a4[mt] = *(const bf16x8*)&s_H[(mt*16 + ar)*LDA + kk*32 + ak];
#pragma unroll
                for (int ntl = 0; ntl < 3; ntl++) {
                    const int col = (wv*3 + ntl)*16 + ar;
                    bf16x8 w = *(const bf16x8*)&W2t[(size_t)col * 768 + cc*192 + kk*32 + ak];
#pragma unroll
                    for (int mt = 0; mt < 4; mt++)
                        accO[ntl][mt] = MFMA(a4[mt], w, accO[ntl][mt]);
                }
            }
        }
        __syncthreads();
    }

    // ---- epilogue: out = accO + b2 + residual, reverse-shift scatter ----
#pragma unroll
    for (int ntl = 0; ntl < 3; ntl++) {
        const int col = (wv*3 + ntl)*16 + ar;
        const float bias = b2f[col];
#pragma unroll
        for (int mt = 0; mt < 4; mt++)
#pragma unroll
            for (int rg = 0; rg < 4; rg++) {
                const int grow = base + mt*16 + rg0 + rg;
                const int w = grow / 49, t = grow - w * 49;
                const int bb = w >> 6, wi = (w >> 3) & 7, wj = w & 7;
                const int pi = t / 7, pj = t - pi * 7;
                const int di = (wi * WSZ + pi + SSH) % HH;
                const int dj = (wj * WSZ + pj + SSH) % HH;
                out[((size_t)bb * LTOT + di * HH + dj) * DIMC + col] =
                    accO[ntl][mt][rg] + bias + bf2f(xattn[(size_t)grow * DIMC + col]);
            }
    }
}

// ---------------------------------------------------------------------------
// Fallback: monolithic fused kernel (2 blocks/CU), if ws too small for xattn.
// ---------------------------------------------------------------------------
__global__ __launch_bounds__(256, 2)
void swin_mono(const float* __restrict__ x,
               const float* __restrict__ qkv_b, const float* __restrict__ proj_b,
               const float* __restrict__ g1, const float* __restrict__ be1,
               const float* __restrict__ g2, const float* __restrict__ be2,
               const float* __restrict__ b1f, const float* __restrict__ b2f,
               const u16* __restrict__ wsw, float* __restrict__ out)
{
    __shared__ __align__(16) u16 s_A[64 * LDA];
    __shared__ __align__(16) u16 s_Q[64 * LDA];
    __shared__ __align__(16) u16 s_R3[64 * LDA];

    float* const Sf  = (float*)s_R3;
    u16*  const PU   = s_R3;
    u16*  const Vt   = s_R3 + 64 * LDPU;
    u16*  const s_H  = s_R3;
    u16*  const s_XW = s_Q;

    const int wid = blockIdx.x;
    const int b  = wid >> 6;
    const int wi = (wid >> 3) & 7;
    const int wj = wid & 7;
    const int tid  = threadIdx.x;
    const int wv   = tid >> 6;
    const int lane = tid & 63;
    const int ar   = lane & 15;
    const int ak   = (lane >> 4) << 3;
    const int rg0  = (lane >> 4) << 2;

    const u16* Wpt = wsw + OFF_PW;
    const u16* W1t = wsw + OFF_W1;
    const u16* W2t = wsw + OFF_W2;

    ln1_gather(x, g1, be1, s_A, b, wi, wj, wv, lane);
    __syncthreads();

    attn_all(s_A, s_Q, Sf, PU, Vt, wsw + OFF_QKV, qkv_b, tid, wv, ar, ak, rg0);

    {
        bf16x8 ao[4][6];
#pragma unroll
        for (int mt = 0; mt < 4; mt++)
#pragma unroll
            for (int kk = 0; kk < 6; kk++)
                ao[mt][kk] = *(const bf16x8*)&s_A[(mt*16 + ar)*LDA + kk*32 + ak];
#pragma unroll
        for (int ntl = 0; ntl < 3; ntl++) {
            const int col = (wv*3 + ntl)*16 + ar;
            const float bias = proj_b[col];
            const u16* wc = Wpt + (size_t)col * 192;
            f32x4 acc[4];
#pragma unroll
            for (int mt = 0; mt < 4; mt++) acc[mt] = 0;
#pragma unroll
            for (int kk = 0; kk < 6; kk++) {
                bf16x8 bh = *(const bf16x8*)&wc[kk*32 + ak];
#pragma unroll
                for (int mt = 0; mt < 4; mt++)
                    acc[mt] = MFMA(ao[mt][kk], bh, acc[mt]);
            }
#pragma unroll
            for (int mt = 0; mt < 4; mt++)
#pragma unroll
                for (int rg = 0; rg < 4; rg++)
                    s_XW[(mt*16 + rg0 + rg)*LDA + col] = f2bf(acc[mt][rg] + bias);
        }
    }
    __syncthreads();

    for (int t = wv; t < NTOK; t += 4) {
        float v0 = bf2f(s_XW[t*LDA + lane      ]);
        float v1 = bf2f(s_XW[t*LDA + lane + 64 ]);
        float v2 = bf2f(s_XW[t*LDA + lane + 128]);
        float s  = v0 + v1 + v2;
        float s2 = v0*v0 + v1*v1 + v2*v2;
#pragma unroll
        for (int off = 32; off > 0; off >>= 1) {
            s  += __shfl_xor(s,  off);
            s2 += __shfl_xor(s2, off);
        }
        const float mu   = s * (1.f / 192.f);
        const float rstd = rsqrtf(s2 * (1.f / 192.f) - mu * mu + 1e-5f);
        s_A[t*LDA + lane      ] = f2bf((v0-mu)*rstd*g2[lane]     + be2[lane]);
        s_A[t*LDA + lane + 64 ] = f2bf((v1-mu)*rstd*g2[lane+64]  + be2[lane+64]);
        s_A[t*LDA + lane + 128] = f2bf((v2-mu)*rstd*g2[lane+128] + be2[lane+128]);
    }
    __syncthreads();

    f32x4 accO[3][4];
#pragma unroll
    for (int i = 0; i < 3; i++)
#pragma unroll
        for (int m = 0; m < 4; m++) accO[i][m] = 0;

    for (int cc = 0; cc < 4; cc++) {
        {
            f32x4 acc1[3][4];
#pragma unroll
            for (int i = 0; i < 3; i++)
#pragma unroll
                for (int m = 0; m < 4; m++) acc1[i][m] = 0;
#pragma unroll
            for (int kk = 0; kk < 6; kk++) {
                bf16x8 a4[4];
#pragma unroll
                for (int mt = 0; mt < 4; mt++)
                    a4[mt] = *(const bf16x8*)&s_A[(mt*16 + ar)*LDA + kk*32 + ak];
#pragma unroll
                for (int ntl = 0; ntl < 3; ntl++) {
                    const int ngl = cc*192 + (wv*3 + ntl)*16 + ar;
                    bf16x8 w = *(const bf16x8*)&W1t[(size_t)ngl * 192 + kk*32 + ak];
#pragma unroll
                    for (int mt = 0; mt < 4; mt++)
                        acc1[ntl][mt] = MFMA(a4[mt], w, acc1[ntl][mt]);
                }
            }
#pragma unroll
            for (int ntl = 0; ntl < 3; ntl++) {
                const int ncol = (wv*3 + ntl)*16 + ar;
                const float bias = b1f[cc*192 + ncol];
#pragma unroll
                for (int mt = 0; mt < 4; mt++)
#pragma unroll
                    for (int rg = 0; rg < 4; rg++) {
                        const float z = acc1[ntl][mt][rg] + bias;
                        const float ge = 0.5f * z * (1.f + erff(z * 0.70710678118654752f));
                        s_H[(mt*16 + rg0 + rg)*LDA + ncol] = f2bf(ge);
                    }
            }
        }
        __syncthreads();
        {
#pragma unroll
            for (int kk = 0; kk < 6; kk++) {
                bf16x8 a4[4];
#pragma unroll
                for (int mt = 0; mt < 4; mt++)
                    a4[mt] = *(const bf16x8*)&s_H[(mt*16 + ar)*LDA + kk*32 + ak];
#pragma unroll
                for (int ntl = 0; ntl < 3; ntl++) {
                    const int col = (wv*3 + ntl)*16 + ar;
                    bf16x8 w = *(const bf16x8*)&W2t[(size_t)col * 768 + cc*192 + kk*32 + ak];
#pragma unroll
                    for (int mt = 0; mt < 4; mt++)
                        accO[ntl][mt] = MFMA(a4[mt], w, accO[ntl][mt]);
                }
            }
        }
        __syncthreads();
    }

#pragma unroll
    for (int ntl = 0; ntl < 3; ntl++) {
        const int col = (wv*3 + ntl)*16 + ar;
        const float bias = b2f[col];
#pragma unroll
        for (int mt = 0; mt < 4; mt++)
#pragma unroll
            for (int rg = 0; rg < 4; rg++) {
                const int row = mt*16 + rg0 + rg;
                if (row < NTOK) {
                    const int pi = row / 7, pj = row - pi * 7;
                    const int di = (wi * WSZ + pi + SSH) % HH;
                    const int dj = (wj * WSZ + pj + SSH) % HH;
                    out[((size_t)b * LTOT + di * HH + dj) * DIMC + col] =
                        accO[ntl][mt][rg] + bias + bf2f(s_XW[row*LDA + col]);
                }
            }
    }
}

extern "C" void kernel_launch(void* const* d_in, const int* in_sizes, int n_in,
                              void* d_out, int out_size, void* d_ws, size_t ws_size,
                              hipStream_t stream)
{
    const float* x      = (const float*)d_in[0];
    const float* qkv_w  = (const float*)d_in[1];
    const float* qkv_b  = (const float*)d_in[2];
    const float* proj_w = (const float*)d_in[3];
    const float* proj_b = (const float*)d_in[4];
    const float* g1     = (const float*)d_in[5];
    const float* be1    = (const float*)d_in[6];
    const float* g2     = (const float*)d_in[7];
    const float* be2    = (const float*)d_in[8];
    const float* w1     = (const float*)d_in[9];
    const float* b1     = (const float*)d_in[10];
    const float* w2     = (const float*)d_in[11];
    const float* b2     = (const float*)d_in[12];
    float* out = (float*)d_out;

    cvt_weights<<<256, 256, 0, stream>>>(qkv_w, proj_w, w1, w2, (u16*)d_ws);

    if (ws_size >= (size_t)WS_BYTES + XATTN_BYTES) {
        u16* xattn = (u16*)d_ws + WS_ELEMS;
        swin_attn<<<NWIN_T, 256, 0, stream>>>(x, qkv_b, proj_b, g1, be1,
                                              (const u16*)d_ws, xattn);
        swin_mlp<<<NTOKENS/64, 256, 0, stream>>>(xattn, g2, be2, b1, b2,
                                                 (const u16*)d_ws, out);
    } else {
        swin_mono<<<NWIN_T, 256, 0, stream>>>(x, qkv_b, proj_b, g1, be1, g2, be2,
                                              b1, b2, (const u16*)d_ws, out);
    }
}

// Round 17
// 347.146 us; speedup vs baseline: 1.2630x; 1.0031x over previous
//
#include <hip/hip_runtime.h>

typedef unsigned short u16;
typedef unsigned int   u32;
typedef __attribute__((ext_vector_type(8))) short bf16x8;
typedef __attribute__((ext_vector_type(4))) float f32x4;

#define DIMC   192
#define HH     56
#define WSZ    7
#define SSH    3
#define NTOK   49
#define NWIN_T 2048
#define HIDDEN 768
#define LTOT   3136
#define NTOKENS 100352

#define LDA    200    // u16 row stride, [64][<=192] tiles (400B rows)
#define LDSS   68     // f32 row stride of S
#define LDPU   136    // u16 view (2*LDSS): hi cols 0-63, lo cols 64-127
#define LDVT   72     // u16 row stride of V^T

// ws layout (u16 elems): bf16 W^T[N][K] (hi only; split-P keeps accuracy)
#define OFF_QKV 0                         // 576 cols * 192
#define OFF_PW  110592                    // + 192 * 192
#define OFF_W1  147456                    // + 768 * 192
#define OFF_W2  294912                    // + 192 * 768
#define WS_ELEMS 442368
#define WS_BYTES (WS_ELEMS * 2)
#define XATTN_ELEMS ((size_t)NWIN_T * NTOK * DIMC)
#define XATTN_BYTES (XATTN_ELEMS * 2)                    // 38.5 MB

#define MFMA(a,b,c) __builtin_amdgcn_mfma_f32_16x16x32_bf16((a),(b),(c),0,0,0)

__device__ __forceinline__ float bf2f(u16 u) {
    union { u32 i; float f; } v; v.i = ((u32)u) << 16; return v.f;
}
__device__ __forceinline__ u16 f2bf(float f) {
    union { float ff; u32 i; } v; v.ff = f;
    u32 x = v.i;
    return (u16)((x + 0x7FFFu + ((x >> 16) & 1u)) >> 16);  // RNE
}

// ---------------------------------------------------------------------------
// Prep: fp32 [K][N] weights -> bf16 W^T [N][K] in ws.
// ---------------------------------------------------------------------------
__global__ void cvt_weights(const float* __restrict__ qkv_w,
                            const float* __restrict__ proj_w,
                            const float* __restrict__ w1,
                            const float* __restrict__ w2,
                            u16* __restrict__ ws)
{
    const int idx = blockIdx.x * blockDim.x + threadIdx.x;
    const int stride = gridDim.x * blockDim.x;
    for (int i = idx; i < 110592; i += stride) {        // qkv [192][576]
        int k = i / 576, n = i - k * 576;
        ws[OFF_QKV + n * 192 + k] = f2bf(qkv_w[i]);
    }
    for (int i = idx; i < 36864; i += stride) {         // proj [192][192]
        int k = i / 192, n = i - k * 192;
        ws[OFF_PW + n * 192 + k] = f2bf(proj_w[i]);
    }
    for (int i = idx; i < 147456; i += stride) {        // w1 [192][768]
        int k = i / 768, n = i - k * 768;
        ws[OFF_W1 + n * 192 + k] = f2bf(w1[i]);
    }
    for (int i = idx; i < 147456; i += stride) {        // w2 [768][192]
        int k = i / 192, n = i - k * 192;
        ws[OFF_W2 + n * 768 + k] = f2bf(w2[i]);
    }
}

// ---------------------------------------------------------------------------
// P1: gather (shift -SSH) + LN1 -> s_A [64][192]; pad rows 49..63 zeroed.
// ---------------------------------------------------------------------------
__device__ __forceinline__ void ln1_gather(
    const float* __restrict__ x, const float* __restrict__ g1,
    const float* __restrict__ be1, u16* __restrict__ s_A,
    int b, int wi, int wj, int wv, int lane)
{
    for (int t = wv; t < 64; t += 4) {
        if (t < NTOK) {
            const int pi = t / 7, pj = t - pi * 7;
            const int si = (wi * WSZ + pi + SSH) % HH;
            const int sj = (wj * WSZ + pj + SSH) % HH;
            const float* src = x + ((size_t)b * LTOT + si * HH + sj) * DIMC;
            float v0 = src[lane], v1 = src[lane + 64], v2 = src[lane + 128];
            float s  = v0 + v1 + v2;
            float s2 = v0 * v0 + v1 * v1 + v2 * v2;
#pragma unroll
            for (int off = 32; off > 0; off >>= 1) {
                s  += __shfl_xor(s,  off);
                s2 += __shfl_xor(s2, off);
            }
            const float mu   = s * (1.f / 192.f);
            const float rstd = rsqrtf(s2 * (1.f / 192.f) - mu * mu + 1e-5f);
            s_A[t*LDA + lane      ] = f2bf((v0-mu)*rstd*g1[lane]     + be1[lane]);
            s_A[t*LDA + lane + 64 ] = f2bf((v1-mu)*rstd*g1[lane+64]  + be1[lane+64]);
            s_A[t*LDA + lane + 128] = f2bf((v2-mu)*rstd*g1[lane+128] + be1[lane+128]);
        } else {
            s_A[t*LDA + lane] = 0; s_A[t*LDA + lane + 64] = 0; s_A[t*LDA + lane + 128] = 0;
        }
    }
}

// ---------------------------------------------------------------------------
// attention: xn frags hoisted to regs; 3 QKV groups x 2 heads; MFMA QK^T,
// wave-parallel fp32 softmax, split hi/lo P MFMA PV. O ends in s_A.
// Caller may alias Sf/PU/Vt INTO s_A (xn is register-hoisted; O written only
// after last PV barrier).
// ---------------------------------------------------------------------------
__device__ __forceinline__ void attn_all(
    u16* __restrict__ s_A, u16* __restrict__ s_Q,
    float* Sf, u16* PU, u16* Vt,
    const u16* __restrict__ Wqkvt, const float* __restrict__ qkv_b,
    int tid, int wv, int ar, int ak, int rg0)
{
    const float scale = 0.1767766952966369f;   // 1/sqrt(32)
    f32x4 o[12];

    bf16x8 ax[4][6];
#pragma unroll
    for (int mt = 0; mt < 4; mt++)
#pragma unroll
        for (int kk = 0; kk < 6; kk++)
            ax[mt][kk] = *(const bf16x8*)&s_A[(mt*16 + ar)*LDA + kk*32 + ak];

#pragma unroll
    for (int G = 0; G < 3; G++) {
#pragma unroll
        for (int tl = 0; tl < 3; tl++) {
            const int tt = wv*3 + tl;
            const int section = tt >> 2, idxq = tt & 3;
            const int gcol = section*192 + G*64 + idxq*16 + ar;
            const int lcol = section*64 + idxq*16 + ar;
            const float bias = qkv_b[gcol];
            const u16* wc = Wqkvt + (size_t)gcol * 192;
            f32x4 acc[4];
#pragma unroll
            for (int mt = 0; mt < 4; mt++) acc[mt] = 0;
#pragma unroll
            for (int kk = 0; kk < 6; kk++) {
                bf16x8 bh = *(const bf16x8*)&wc[kk*32 + ak];
#pragma unroll
                for (int mt = 0; mt < 4; mt++)
                    acc[mt] = MFMA(ax[mt][kk], bh, acc[mt]);
            }
#pragma unroll
            for (int mt = 0; mt < 4; mt++)
#pragma unroll
                for (int rg = 0; rg < 4; rg++)
                    s_Q[(mt*16 + rg0 + rg)*LDA + lcol] = f2bf(acc[mt][rg] + bias);
        }
        __syncthreads();

#pragma unroll
        for (int HL = 0; HL < 2; HL++) {
            {
                bf16x8 bk = *(const bf16x8*)&s_Q[(wv*16 + ar)*LDA + 64 + HL*32 + ak];
#pragma unroll
                for (int mt = 0; mt < 4; mt++) {
                    bf16x8 aq = *(const bf16x8*)&s_Q[(mt*16 + ar)*LDA + HL*32 + ak];
                    f32x4 sa; sa = 0;
                    sa = MFMA(aq, bk, sa);
#pragma unroll
                    for (int rg = 0; rg < 4; rg++)
                        Sf[(mt*16 + rg0 + rg)*LDSS + wv*16 + ar] = sa[rg] * scale;
                }
            }
            __syncthreads();
            {
                const int row = tid >> 2, sub = tid & 3;
                if (row < NTOK) {
                    float e[16]; float m = -1e30f;
#pragma unroll
                    for (int i = 0; i < 16; i++) {
                        const int j = sub + 4*i;
                        e[i] = (j < NTOK) ? Sf[row*LDSS + j] : -1e30f;
                        m = fmaxf(m, e[i]);
                    }
                    m = fmaxf(m, __shfl_xor(m, 1));
                    m = fmaxf(m, __shfl_xor(m, 2));
                    float sum = 0.f;
#pragma unroll
                    for (int i = 0; i < 16; i++) { e[i] = __expf(e[i] - m); sum += e[i]; }
                    sum += __shfl_xor(sum, 1);
                    sum += __shfl_xor(sum, 2);
                    const float inv = 1.f / sum;
#pragma unroll
                    for (int i = 0; i < 16; i++) {
                        const int j = sub + 4*i;
                        const float p = e[i] * inv;   // 0 for j>=49 -> pad cols zero
                        const u16 hb = f2bf(p);
                        PU[row*LDPU + j] = hb;
                        PU[row*LDPU + 64 + j] = f2bf(p - bf2f(hb));
                    }
                }
                for (int i2 = tid; i2 < 2048; i2 += 256) {
                    const int d = i2 & 31, j = i2 >> 5;
                    Vt[d*LDVT + j] = (j < NTOK) ? s_Q[j*LDA + 128 + HL*32 + d] : (u16)0;
                }
            }
            __syncthreads();
            {
                const int dcol = (wv & 1)*16 + ar;
                const int mtb = (wv >> 1) << 1;
#pragma unroll
                for (int mi = 0; mi < 2; mi++) {
                    f32x4 accv; accv = 0;
#pragma unroll
                    for (int kk = 0; kk < 2; kk++) {
                        bf16x8 ph = *(const bf16x8*)&PU[((mtb+mi)*16 + ar)*LDPU + kk*32 + ak];
                        bf16x8 pl = *(const bf16x8*)&PU[((mtb+mi)*16 + ar)*LDPU + 64 + kk*32 + ak];
                        bf16x8 bv = *(const bf16x8*)&Vt[dcol*LDVT + kk*32 + ak];
                        accv = MFMA(ph, bv, accv);
                        accv = MFMA(pl, bv, accv);
                    }
                    o[(G*2 + HL)*2 + mi] = accv;
                }
            }
            __syncthreads();
        }
    }

    {
        const int mtb = (wv >> 1) << 1;
        const int cbase = (wv & 1)*16 + ar;
#pragma unroll
        for (int hp = 0; hp < 6; hp++) {
            const int col = hp*32 + cbase;
#pragma unroll
            for (int mi = 0; mi < 2; mi++)
#pragma unroll
                for (int rg = 0; rg < 4; rg++)
                    s_A[((mtb+mi)*16 + rg0 + rg)*LDA + col] = f2bf(o[hp*2 + mi][rg]);
        }
    }
    __syncthreads();
}

// ---------------------------------------------------------------------------
// K1: LN1 + QKV + attention + proj -> xattn. S/P/Vt alias into s_A ->
// 51.2 KB LDS (HW gives 3 blocks/CU); launch_bounds(256,2) keeps regalloc
// free (~128 VGPR, no spill). Direct-measured ~137 us. UNCHANGED.
// ---------------------------------------------------------------------------
__global__ __launch_bounds__(256, 2)
void swin_attn(const float* __restrict__ x,
               const float* __restrict__ qkv_b, const float* __restrict__ proj_b,
               const float* __restrict__ g1, const float* __restrict__ be1,
               const u16* __restrict__ wsw, u16* __restrict__ xattn)
{
    __shared__ __align__(16) u16 s_A[64 * LDA];                 // 25.6 KB
    __shared__ __align__(16) u16 s_Q[64 * LDA];                 // 25.6 KB

    float* const Sf = (float*)s_A;
    u16*  const PU  = s_A;
    u16*  const Vt  = s_A + 64 * LDPU;

    const int wid = blockIdx.x;
    const int b  = wid >> 6;
    const int wi = (wid >> 3) & 7;
    const int wj = wid & 7;
    const int tid  = threadIdx.x;
    const int wv   = tid >> 6;
    const int lane = tid & 63;
    const int ar   = lane & 15;
    const int ak   = (lane >> 4) << 3;
    const int rg0  = (lane >> 4) << 2;

    ln1_gather(x, g1, be1, s_A, b, wi, wj, wv, lane);
    __syncthreads();

    attn_all(s_A, s_Q, Sf, PU, Vt, wsw + OFF_QKV, qkv_b, tid, wv, ar, ak, rg0);

    // ---- proj: XW = O @ Wp + b -> global xattn (bf16) ----
    {
        const u16* Wpt = wsw + OFF_PW;
        bf16x8 ao[4][6];
#pragma unroll
        for (int mt = 0; mt < 4; mt++)
#pragma unroll
            for (int kk = 0; kk < 6; kk++)
                ao[mt][kk] = *(const bf16x8*)&s_A[(mt*16 + ar)*LDA + kk*32 + ak];
#pragma unroll
        for (int ntl = 0; ntl < 3; ntl++) {
            const int col = (wv*3 + ntl)*16 + ar;
            const float bias = proj_b[col];
            const u16* wc = Wpt + (size_t)col * 192;
            f32x4 acc[4];
#pragma unroll
            for (int mt = 0; mt < 4; mt++) acc[mt] = 0;
#pragma unroll
            for (int kk = 0; kk < 6; kk++) {
                bf16x8 bh = *(const bf16x8*)&wc[kk*32 + ak];
#pragma unroll
                for (int mt = 0; mt < 4; mt++)
                    acc[mt] = MFMA(ao[mt][kk], bh, acc[mt]);
            }
#pragma unroll
            for (int mt = 0; mt < 4; mt++)
#pragma unroll
                for (int rg = 0; rg < 4; rg++) {
                    const int row = mt*16 + rg0 + rg;
                    if (row < NTOK)
                        xattn[((size_t)wid * NTOK + row) * DIMC + col] =
                            f2bf(acc[mt][rg] + bias);
                }
        }
    }
}

// ---------------------------------------------------------------------------
// K2: LN2 + MLP + residual — r9 structure (direct-measured 206 us) + two
// strictly-work-removing tweaks: s_dest table (epilogue div/mod hoisted,
// validated in r15's bundle) and no trailing barrier after the last chunk.
// erff gelu, kk-outer a4 reuse, 51.2 KB LDS, (256,3), VGPR ~80 no spill.
// ---------------------------------------------------------------------------
__global__ __launch_bounds__(256, 3)
void swin_mlp(const u16* __restrict__ xattn,
              const float* __restrict__ g2, const float* __restrict__ be2,
              const float* __restrict__ b1f, const float* __restrict__ b2f,
              const u16* __restrict__ wsw, float* __restrict__ out)
{
    __shared__ __align__(16) u16 s_X[64 * LDA];    // 25.6 KB (xln)
    __shared__ __align__(16) u16 s_H[64 * LDA];    // 25.6 KB (h 192-col chunk)
    __shared__ u32 s_dest[64];                     // per-row out base offsets

    const int tid  = threadIdx.x;
    const int wv   = tid >> 6;
    const int lane = tid & 63;
    const int ar   = lane & 15;
    const int ak   = (lane >> 4) << 3;
    const int rg0  = (lane >> 4) << 2;
    const int base = blockIdx.x * 64;
    const u16* W1t = wsw + OFF_W1;
    const u16* W2t = wsw + OFF_W2;

    // ---- LN2 over 64 token rows + dest-table fill ----
    for (int t = wv; t < 64; t += 4) {
        const u16* src = xattn + (size_t)(base + t) * DIMC;
        float v0 = bf2f(src[lane]);
        float v1 = bf2f(src[lane + 64]);
        float v2 = bf2f(src[lane + 128]);
        float s  = v0 + v1 + v2;
        float s2 = v0*v0 + v1*v1 + v2*v2;
#pragma unroll
        for (int off = 32; off > 0; off >>= 1) {
            s  += __shfl_xor(s,  off);
            s2 += __shfl_xor(s2, off);
        }
        const float mu   = s * (1.f / 192.f);
        const float rstd = rsqrtf(s2 * (1.f / 192.f) - mu * mu + 1e-5f);
        s_X[t*LDA + lane      ] = f2bf((v0-mu)*rstd*g2[lane]     + be2[lane]);
        s_X[t*LDA + lane + 64 ] = f2bf((v1-mu)*rstd*g2[lane+64]  + be2[lane+64]);
        s_X[t*LDA + lane + 128] = f2bf((v2-mu)*rstd*g2[lane+128] + be2[lane+128]);
    }
    if (tid < 64) {
        const int grow = base + tid;
        const int w = grow / 49, t = grow - w * 49;
        const int bb = w >> 6, wi = (w >> 3) & 7, wj = w & 7;
        const int pi = t / 7, pj = t - pi * 7;
        const int di = (wi * WSZ + pi + SSH) % HH;
        const int dj = (wj * WSZ + pj + SSH) % HH;
        s_dest[tid] = (u32)((bb * LTOT + di * HH + dj) * DIMC);
    }
    __syncthreads();

    // ---- MLP: 4 hidden-chunks of 192; accO in regs across chunks ----
    f32x4 accO[3][4];
#pragma unroll
    for (int i = 0; i < 3; i++)
#pragma unroll
        for (int m = 0; m < 4; m++) accO[i][m] = 0;

    for (int cc = 0; cc < 4; cc++) {
        // MLP1 chunk: 3 col-tiles per wave, A-frag reused across tiles per kk
        {
            f32x4 acc1[3][4];
#pragma unroll
            for (int i = 0; i < 3; i++)
#pragma unroll
                for (int m = 0; m < 4; m++) acc1[i][m] = 0;
#pragma unroll
            for (int kk = 0; kk < 6; kk++) {
                bf16x8 a4[4];
#pragma unroll
                for (int mt = 0; mt < 4; mt++)
                    a4[mt] = *(const bf16x8*)&s_X[(mt*16 + ar)*LDA + kk*32 + ak];
#pragma unroll
                for (int ntl = 0; ntl < 3; ntl++) {
                    const int ngl = cc*192 + (wv*3 + ntl)*16 + ar;
                    bf16x8 w = *(const bf16x8*)&W1t[(size_t)ngl * 192 + kk*32 + ak];
#pragma unroll
                    for (int mt = 0; mt < 4; mt++)
                        acc1[ntl][mt] = MFMA(a4[mt], w, acc1[ntl][mt]);
                }
            }
#pragma unroll
            for (int ntl = 0; ntl < 3; ntl++) {
                const int ncol = (wv*3 + ntl)*16 + ar;
                const float bias = b1f[cc*192 + ncol];
#pragma unroll
                for (int mt = 0; mt < 4; mt++)
#pragma unroll
                    for (int rg = 0; rg < 4; rg++) {
                        const float z = acc1[ntl][mt][rg] + bias;
                        const float ge = 0.5f * z * (1.f + erff(z * 0.70710678118654752f));
                        s_H[(mt*16 + rg0 + rg)*LDA + ncol] = f2bf(ge);
                    }
            }
        }
        __syncthreads();
        // MLP2 partial over this 192-wide K chunk (kk-outer, a4 reuse)
        {
#pragma unroll
            for (int kk = 0; kk < 6; kk++) {
                bf16x8 a4[4];
#pragma unroll
                for (int mt = 0; mt < 4; mt++)
                    a4[mt] = *(const bf16x8*)&s_H[(mt*16 + ar)*LDA + kk*32 + ak];
#pragma unroll
                for (int ntl = 0; ntl < 3; ntl++) {
                    const int col = (wv*3 + ntl)*16 + ar;
                    bf16x8 w = *(const bf16x8*)&W2t[(size_t)col * 768 + cc*192 + kk*32 + ak];
#pragma unroll
                    for (int mt = 0; mt < 4; mt++)
                        accO[ntl][mt] = MFMA(a4[mt], w, accO[ntl][mt]);
                }
            }
        }
        if (cc < 3) __syncthreads();   // last chunk: epilogue reads only regs+global
    }

    // ---- epilogue: out = accO + b2 + residual, via dest table ----
#pragma unroll
    for (int ntl = 0; ntl < 3; ntl++) {
        const int col = (wv*3 + ntl)*16 + ar;
        const float bias = b2f[col];
#pragma unroll
        for (int mt = 0; mt < 4; mt++)
#pragma unroll
            for (int rg = 0; rg < 4; rg++) {
                const int row = mt*16 + rg0 + rg;            // block-local
                const size_t grow = (size_t)base + row;
                out[(size_t)s_dest[row] + col] =
                    accO[ntl][mt][rg] + bias + bf2f(xattn[grow * DIMC + col]);
            }
    }
}

// ---------------------------------------------------------------------------
// Fallback: monolithic fused kernel (2 blocks/CU), if ws too small for xattn.
// ---------------------------------------------------------------------------
__global__ __launch_bounds__(256, 2)
void swin_mono(const float* __restrict__ x,
               const float* __restrict__ qkv_b, const float* __restrict__ proj_b,
               const float* __restrict__ g1, const float* __restrict__ be1,
               const float* __restrict__ g2, const float* __restrict__ be2,
               const float* __restrict__ b1f, const float* __restrict__ b2f,
               const u16* __restrict__ wsw, float* __restrict__ out)
{
    __shared__ __align__(16) u16 s_A[64 * LDA];
    __shared__ __align__(16) u16 s_Q[64 * LDA];
    __shared__ __align__(16) u16 s_R3[64 * LDA];

    float* const Sf  = (float*)s_R3;
    u16*  const PU   = s_R3;
    u16*  const Vt   = s_R3 + 64 * LDPU;
    u16*  const s_H  = s_R3;
    u16*  const s_XW = s_Q;

    const int wid = blockIdx.x;
    const int b  = wid >> 6;
    const int wi = (wid >> 3) & 7;
    const int wj = wid & 7;
    const int tid  = threadIdx.x;
    const int wv   = tid >> 6;
    const int lane = tid & 63;
    const int ar   = lane & 15;
    const int ak   = (lane >> 4) << 3;
    const int rg0  = (lane >> 4) << 2;

    const u16* Wpt = wsw + OFF_PW;
    const u16* W1t = wsw + OFF_W1;
    const u16* W2t = wsw + OFF_W2;

    ln1_gather(x, g1, be1, s_A, b, wi, wj, wv, lane);
    __syncthreads();

    attn_all(s_A, s_Q, Sf, PU, Vt, wsw + OFF_QKV, qkv_b, tid, wv, ar, ak, rg0);

    {
        bf16x8 ao[4][6];
#pragma unroll
        for (int mt = 0; mt < 4; mt++)
#pragma unroll
            for (int kk = 0; kk < 6; kk++)
                ao[mt][kk] = *(const bf16x8*)&s_A[(mt*16 + ar)*LDA + kk*32 + ak];
#pragma unroll
        for (int ntl = 0; ntl < 3; ntl++) {
            const int col = (wv*3 + ntl)*16 + ar;
            const float bias = proj_b[col];
            const u16* wc = Wpt + (size_t)col * 192;
            f32x4 acc[4];
#pragma unroll
            for (int mt = 0; mt < 4; mt++) acc[mt] = 0;
#pragma unroll
            for (int kk = 0; kk < 6; kk++) {
                bf16x8 bh = *(const bf16x8*)&wc[kk*32 + ak];
#pragma unroll
                for (int mt = 0; mt < 4; mt++)
                    acc[mt] = MFMA(ao[mt][kk], bh, acc[mt]);
            }
#pragma unroll
            for (int mt = 0; mt < 4; mt++)
#pragma unroll
                for (int rg = 0; rg < 4; rg++)
                    s_XW[(mt*16 + rg0 + rg)*LDA + col] = f2bf(acc[mt][rg] + bias);
        }
    }
    __syncthreads();

    for (int t = wv; t < NTOK; t += 4) {
        float v0 = bf2f(s_XW[t*LDA + lane      ]);
        float v1 = bf2f(s_XW[t*LDA + lane + 64 ]);
        float v2 = bf2f(s_XW[t*LDA + lane + 128]);
        float s  = v0 + v1 + v2;
        float s2 = v0*v0 + v1*v1 + v2*v2;
#pragma unroll
        for (int off = 32; off > 0; off >>= 1) {
            s  += __shfl_xor(s,  off);
            s2 += __shfl_xor(s2, off);
        }
        const float mu   = s * (1.f / 192.f);
        const float rstd = rsqrtf(s2 * (1.f / 192.f) - mu * mu + 1e-5f);
        s_A[t*LDA + lane      ] = f2bf((v0-mu)*rstd*g2[lane]     + be2[lane]);
        s_A[t*LDA + lane + 64 ] = f2bf((v1-mu)*rstd*g2[lane+64]  + be2[lane+64]);
        s_A[t*LDA + lane + 128] = f2bf((v2-mu)*rstd*g2[lane+128] + be2[lane+128]);
    }
    __syncthreads();

    f32x4 accO[3][4];
#pragma unroll
    for (int i = 0; i < 3; i++)
#pragma unroll
        for (int m = 0; m < 4; m++) accO[i][m] = 0;

    for (int cc = 0; cc < 4; cc++) {
        {
            f32x4 acc1[3][4];
#pragma unroll
            for (int i = 0; i < 3; i++)
#pragma unroll
                for (int m = 0; m < 4; m++) acc1[i][m] = 0;
#pragma unroll
            for (int kk = 0; kk < 6; kk++) {
                bf16x8 a4[4];
#pragma unroll
                for (int mt = 0; mt < 4; mt++)
                    a4[mt] = *(const bf16x8*)&s_A[(mt*16 + ar)*LDA + kk*32 + ak];
#pragma unroll
                for (int ntl = 0; ntl < 3; ntl++) {
                    const int ngl = cc*192 + (wv*3 + ntl)*16 + ar;
                    bf16x8 w = *(const bf16x8*)&W1t[(size_t)ngl * 192 + kk*32 + ak];
#pragma unroll
                    for (int mt = 0; mt < 4; mt++)
                        acc1[ntl][mt] = MFMA(a4[mt], w, acc1[ntl][mt]);
                }
            }
#pragma unroll
            for (int ntl = 0; ntl < 3; ntl++) {
                const int ncol = (wv*3 + ntl)*16 + ar;
                const float bias = b1f[cc*192 + ncol];
#pragma unroll
                for (int mt = 0; mt < 4; mt++)
#pragma unroll
                    for (int rg = 0; rg < 4; rg++) {
                        const float z = acc1[ntl][mt][rg] + bias;
                        const float ge = 0.5f * z * (1.f + erff(z * 0.70710678118654752f));
                        s_H[(mt*16 + rg0 + rg)*LDA + ncol] = f2bf(ge);
                    }
            }
        }
        __syncthreads();
        {
#pragma unroll
            for (int kk = 0; kk < 6; kk++) {
                bf16x8 a4[4];
#pragma unroll
                for (int mt = 0; mt < 4; mt++)
                    a4[mt] = *(const bf16x8*)&s_H[(mt*16 + ar)*LDA + kk*32 + ak];
#pragma unroll
                for (int ntl = 0; ntl < 3; ntl++) {
                    const int col = (wv*3 + ntl)*16 + ar;
                    bf16x8 w = *(const bf16x8*)&W2t[(size_t)col * 768 + cc*192 + kk*32 + ak];
#pragma unroll
                    for (int mt = 0; mt < 4; mt++)
                        accO[ntl][mt] = MFMA(a4[mt], w, accO[ntl][mt]);
                }
            }
        }
        __syncthreads();
    }

#pragma unroll
    for (int ntl = 0; ntl < 3; ntl++) {
        const int col = (wv*3 + ntl)*16 + ar;
        const float bias = b2f[col];
#pragma unroll
        for (int mt = 0; mt < 4; mt++)
#pragma unroll
            for (int rg = 0; rg < 4; rg++) {
                const int row = mt*16 + rg0 + rg;
                if (row < NTOK) {
                    const int pi = row / 7, pj = row - pi * 7;
                    const int di = (wi * WSZ + pi + SSH) % HH;
                    const int dj = (wj * WSZ + pj + SSH) % HH;
                    out[((size_t)b * LTOT + di * HH + dj) * DIMC + col] =
                        accO[ntl][mt][rg] + bias + bf2f(s_XW[row*LDA + col]);
                }
            }
    }
}

extern "C" void kernel_launch(void* const* d_in, const int* in_sizes, int n_in,
                              void* d_out, int out_size, void* d_ws, size_t ws_size,
                              hipStream_t stream)
{
    const float* x      = (const float*)d_in[0];
    const float* qkv_w  = (const float*)d_in[1];
    const float* qkv_b  = (const float*)d_in[2];
    const float* proj_w = (const float*)d_in[3];
    const float* proj_b = (const float*)d_in[4];
    const float* g1     = (const float*)d_in[5];
    const float* be1    = (const float*)d_in[6];
    const float* g2     = (const float*)d_in[7];
    const float* be2    = (const float*)d_in[8];
    const float* w1     = (const float*)d_in[9];
    const float* b1     = (const float*)d_in[10];
    const float* w2     = (const float*)d_in[11];
    const float* b2     = (const float*)d_in[12];
    float* out = (float*)d_out;

    cvt_weights<<<256, 256, 0, stream>>>(qkv_w, proj_w, w1, w2, (u16*)d_ws);

    if (ws_size >= (size_t)WS_BYTES + XATTN_BYTES) {
        u16* xattn = (u16*)d_ws + WS_ELEMS;
        swin_attn<<<NWIN_T, 256, 0, stream>>>(x, qkv_b, proj_b, g1, be1,
                                              (const u16*)d_ws, xattn);
        swin_mlp<<<NTOKENS/64, 256, 0, stream>>>(xattn, g2, be2, b1, b2,
                                                 (const u16*)d_ws, out);
    } else {
        swin_mono<<<NWIN_T, 256, 0, stream>>>(x, qkv_b, proj_b, g1, be1, g2, be2,
                                              b1, b2, (const u16*)d_ws, out);
    }
}

// Round 18
// 346.798 us; speedup vs baseline: 1.2643x; 1.0010x over previous
//
#include <hip/hip_runtime.h>

typedef unsigned short u16;
typedef unsigned int   u32;
typedef __attribute__((ext_vector_type(8))) short bf16x8;
typedef __attribute__((ext_vector_type(4))) float f32x4;

#define DIMC   192
#define HH     56
#define WSZ    7
#define SSH    3
#define NTOK   49
#define NWIN_T 2048
#define HIDDEN 768
#define LTOT   3136
#define NTOKENS 100352

#define LDA    200    // u16 row stride, [64][<=192] tiles (400B rows)
#define LDSS   68     // f32 row stride of S
#define LDPU   136    // u16 view (2*LDSS): hi cols 0-63, lo cols 64-127
#define LDVT   72     // u16 row stride of V^T

// ws layout (u16 elems): bf16 W^T[N][K] (hi only; split-P keeps accuracy)
#define OFF_QKV 0                         // 576 cols * 192
#define OFF_PW  110592                    // + 192 * 192
#define OFF_W1  147456                    // + 768 * 192
#define OFF_W2  294912                    // + 192 * 768
#define WS_ELEMS 442368
#define WS_BYTES (WS_ELEMS * 2)
#define XATTN_ELEMS ((size_t)NWIN_T * NTOK * DIMC)
#define XATTN_BYTES (XATTN_ELEMS * 2)                    // 38.5 MB

#define MFMA(a,b,c) __builtin_amdgcn_mfma_f32_16x16x32_bf16((a),(b),(c),0,0,0)

__device__ __forceinline__ float bf2f(u16 u) {
    union { u32 i; float f; } v; v.i = ((u32)u) << 16; return v.f;
}
__device__ __forceinline__ u16 f2bf(float f) {
    union { float ff; u32 i; } v; v.ff = f;
    u32 x = v.i;
    return (u16)((x + 0x7FFFu + ((x >> 16) & 1u)) >> 16);  // RNE
}

// ---------------------------------------------------------------------------
// Prep: fp32 [K][N] weights -> bf16 W^T [N][K] in ws.
// ---------------------------------------------------------------------------
__global__ void cvt_weights(const float* __restrict__ qkv_w,
                            const float* __restrict__ proj_w,
                            const float* __restrict__ w1,
                            const float* __restrict__ w2,
                            u16* __restrict__ ws)
{
    const int idx = blockIdx.x * blockDim.x + threadIdx.x;
    const int stride = gridDim.x * blockDim.x;
    for (int i = idx; i < 110592; i += stride) {        // qkv [192][576]
        int k = i / 576, n = i - k * 576;
        ws[OFF_QKV + n * 192 + k] = f2bf(qkv_w[i]);
    }
    for (int i = idx; i < 36864; i += stride) {         // proj [192][192]
        int k = i / 192, n = i - k * 192;
        ws[OFF_PW + n * 192 + k] = f2bf(proj_w[i]);
    }
    for (int i = idx; i < 147456; i += stride) {        // w1 [192][768]
        int k = i / 768, n = i - k * 768;
        ws[OFF_W1 + n * 192 + k] = f2bf(w1[i]);
    }
    for (int i = idx; i < 147456; i += stride) {        // w2 [768][192]
        int k = i / 192, n = i - k * 192;
        ws[OFF_W2 + n * 768 + k] = f2bf(w2[i]);
    }
}

// ---------------------------------------------------------------------------
// P1: gather (shift -SSH) + LN1 -> s_A [64][192]; pad rows 49..63 zeroed.
// ---------------------------------------------------------------------------
__device__ __forceinline__ void ln1_gather(
    const float* __restrict__ x, const float* __restrict__ g1,
    const float* __restrict__ be1, u16* __restrict__ s_A,
    int b, int wi, int wj, int wv, int lane)
{
    for (int t = wv; t < 64; t += 4) {
        if (t < NTOK) {
            const int pi = t / 7, pj = t - pi * 7;
            const int si = (wi * WSZ + pi + SSH) % HH;
            const int sj = (wj * WSZ + pj + SSH) % HH;
            const float* src = x + ((size_t)b * LTOT + si * HH + sj) * DIMC;
            float v0 = src[lane], v1 = src[lane + 64], v2 = src[lane + 128];
            float s  = v0 + v1 + v2;
            float s2 = v0 * v0 + v1 * v1 + v2 * v2;
#pragma unroll
            for (int off = 32; off > 0; off >>= 1) {
                s  += __shfl_xor(s,  off);
                s2 += __shfl_xor(s2, off);
            }
            const float mu   = s * (1.f / 192.f);
            const float rstd = rsqrtf(s2 * (1.f / 192.f) - mu * mu + 1e-5f);
            s_A[t*LDA + lane      ] = f2bf((v0-mu)*rstd*g1[lane]     + be1[lane]);
            s_A[t*LDA + lane + 64 ] = f2bf((v1-mu)*rstd*g1[lane+64]  + be1[lane+64]);
            s_A[t*LDA + lane + 128] = f2bf((v2-mu)*rstd*g1[lane+128] + be1[lane+128]);
        } else {
            s_A[t*LDA + lane] = 0; s_A[t*LDA + lane + 64] = 0; s_A[t*LDA + lane + 128] = 0;
        }
    }
}

// ---------------------------------------------------------------------------
// attention: xn frags hoisted to regs; 3 QKV groups x 2 heads; MFMA QK^T,
// wave-parallel fp32 softmax, split hi/lo P MFMA PV. O ends in s_A.
// Caller may alias Sf/PU/Vt INTO s_A (xn is register-hoisted; O written only
// after last PV barrier).
// ---------------------------------------------------------------------------
__device__ __forceinline__ void attn_all(
    u16* __restrict__ s_A, u16* __restrict__ s_Q,
    float* Sf, u16* PU, u16* Vt,
    const u16* __restrict__ Wqkvt, const float* __restrict__ qkv_b,
    int tid, int wv, int ar, int ak, int rg0)
{
    const float scale = 0.1767766952966369f;   // 1/sqrt(32)
    f32x4 o[12];

    bf16x8 ax[4][6];
#pragma unroll
    for (int mt = 0; mt < 4; mt++)
#pragma unroll
        for (int kk = 0; kk < 6; kk++)
            ax[mt][kk] = *(const bf16x8*)&s_A[(mt*16 + ar)*LDA + kk*32 + ak];

#pragma unroll
    for (int G = 0; G < 3; G++) {
#pragma unroll
        for (int tl = 0; tl < 3; tl++) {
            const int tt = wv*3 + tl;
            const int section = tt >> 2, idxq = tt & 3;
            const int gcol = section*192 + G*64 + idxq*16 + ar;
            const int lcol = section*64 + idxq*16 + ar;
            const float bias = qkv_b[gcol];
            const u16* wc = Wqkvt + (size_t)gcol * 192;
            f32x4 acc[4];
#pragma unroll
            for (int mt = 0; mt < 4; mt++) acc[mt] = 0;
#pragma unroll
            for (int kk = 0; kk < 6; kk++) {
                bf16x8 bh = *(const bf16x8*)&wc[kk*32 + ak];
#pragma unroll
                for (int mt = 0; mt < 4; mt++)
                    acc[mt] = MFMA(ax[mt][kk], bh, acc[mt]);
            }
#pragma unroll
            for (int mt = 0; mt < 4; mt++)
#pragma unroll
                for (int rg = 0; rg < 4; rg++)
                    s_Q[(mt*16 + rg0 + rg)*LDA + lcol] = f2bf(acc[mt][rg] + bias);
        }
        __syncthreads();

#pragma unroll
        for (int HL = 0; HL < 2; HL++) {
            {
                bf16x8 bk = *(const bf16x8*)&s_Q[(wv*16 + ar)*LDA + 64 + HL*32 + ak];
#pragma unroll
                for (int mt = 0; mt < 4; mt++) {
                    bf16x8 aq = *(const bf16x8*)&s_Q[(mt*16 + ar)*LDA + HL*32 + ak];
                    f32x4 sa; sa = 0;
                    sa = MFMA(aq, bk, sa);
#pragma unroll
                    for (int rg = 0; rg < 4; rg++)
                        Sf[(mt*16 + rg0 + rg)*LDSS + wv*16 + ar] = sa[rg] * scale;
                }
            }
            __syncthreads();
            {
                const int row = tid >> 2, sub = tid & 3;
                if (row < NTOK) {
                    float e[16]; float m = -1e30f;
#pragma unroll
                    for (int i = 0; i < 16; i++) {
                        const int j = sub + 4*i;
                        e[i] = (j < NTOK) ? Sf[row*LDSS + j] : -1e30f;
                        m = fmaxf(m, e[i]);
                    }
                    m = fmaxf(m, __shfl_xor(m, 1));
                    m = fmaxf(m, __shfl_xor(m, 2));
                    float sum = 0.f;
#pragma unroll
                    for (int i = 0; i < 16; i++) { e[i] = __expf(e[i] - m); sum += e[i]; }
                    sum += __shfl_xor(sum, 1);
                    sum += __shfl_xor(sum, 2);
                    const float inv = 1.f / sum;
#pragma unroll
                    for (int i = 0; i < 16; i++) {
                        const int j = sub + 4*i;
                        const float p = e[i] * inv;   // 0 for j>=49 -> pad cols zero
                        const u16 hb = f2bf(p);
                        PU[row*LDPU + j] = hb;
                        PU[row*LDPU + 64 + j] = f2bf(p - bf2f(hb));
                    }
                }
                for (int i2 = tid; i2 < 2048; i2 += 256) {
                    const int d = i2 & 31, j = i2 >> 5;
                    Vt[d*LDVT + j] = (j < NTOK) ? s_Q[j*LDA + 128 + HL*32 + d] : (u16)0;
                }
            }
            __syncthreads();
            {
                const int dcol = (wv & 1)*16 + ar;
                const int mtb = (wv >> 1) << 1;
#pragma unroll
                for (int mi = 0; mi < 2; mi++) {
                    f32x4 accv; accv = 0;
#pragma unroll
                    for (int kk = 0; kk < 2; kk++) {
                        bf16x8 ph = *(const bf16x8*)&PU[((mtb+mi)*16 + ar)*LDPU + kk*32 + ak];
                        bf16x8 pl = *(const bf16x8*)&PU[((mtb+mi)*16 + ar)*LDPU + 64 + kk*32 + ak];
                        bf16x8 bv = *(const bf16x8*)&Vt[dcol*LDVT + kk*32 + ak];
                        accv = MFMA(ph, bv, accv);
                        accv = MFMA(pl, bv, accv);
                    }
                    o[(G*2 + HL)*2 + mi] = accv;
                }
            }
            __syncthreads();
        }
    }

    {
        const int mtb = (wv >> 1) << 1;
        const int cbase = (wv & 1)*16 + ar;
#pragma unroll
        for (int hp = 0; hp < 6; hp++) {
            const int col = hp*32 + cbase;
#pragma unroll
            for (int mi = 0; mi < 2; mi++)
#pragma unroll
                for (int rg = 0; rg < 4; rg++)
                    s_A[((mtb+mi)*16 + rg0 + rg)*LDA + col] = f2bf(o[hp*2 + mi][rg]);
        }
    }
    __syncthreads();
}

// ---------------------------------------------------------------------------
// K1: LN1 + QKV + attention + proj -> xattn. S/P/Vt alias into s_A ->
// 51.2 KB LDS (HW gives 3 blocks/CU); launch_bounds(256,2) keeps regalloc
// free (~128 VGPR, no spill). Direct-measured ~137 us.
// ---------------------------------------------------------------------------
__global__ __launch_bounds__(256, 2)
void swin_attn(const float* __restrict__ x,
               const float* __restrict__ qkv_b, const float* __restrict__ proj_b,
               const float* __restrict__ g1, const float* __restrict__ be1,
               const u16* __restrict__ wsw, u16* __restrict__ xattn)
{
    __shared__ __align__(16) u16 s_A[64 * LDA];                 // 25.6 KB
    __shared__ __align__(16) u16 s_Q[64 * LDA];                 // 25.6 KB

    float* const Sf = (float*)s_A;
    u16*  const PU  = s_A;
    u16*  const Vt  = s_A + 64 * LDPU;

    const int wid = blockIdx.x;
    const int b  = wid >> 6;
    const int wi = (wid >> 3) & 7;
    const int wj = wid & 7;
    const int tid  = threadIdx.x;
    const int wv   = tid >> 6;
    const int lane = tid & 63;
    const int ar   = lane & 15;
    const int ak   = (lane >> 4) << 3;
    const int rg0  = (lane >> 4) << 2;

    ln1_gather(x, g1, be1, s_A, b, wi, wj, wv, lane);
    __syncthreads();

    attn_all(s_A, s_Q, Sf, PU, Vt, wsw + OFF_QKV, qkv_b, tid, wv, ar, ak, rg0);

    // ---- proj: XW = O @ Wp + b -> global xattn (bf16) ----
    {
        const u16* Wpt = wsw + OFF_PW;
        bf16x8 ao[4][6];
#pragma unroll
        for (int mt = 0; mt < 4; mt++)
#pragma unroll
            for (int kk = 0; kk < 6; kk++)
                ao[mt][kk] = *(const bf16x8*)&s_A[(mt*16 + ar)*LDA + kk*32 + ak];
#pragma unroll
        for (int ntl = 0; ntl < 3; ntl++) {
            const int col = (wv*3 + ntl)*16 + ar;
            const float bias = proj_b[col];
            const u16* wc = Wpt + (size_t)col * 192;
            f32x4 acc[4];
#pragma unroll
            for (int mt = 0; mt < 4; mt++) acc[mt] = 0;
#pragma unroll
            for (int kk = 0; kk < 6; kk++) {
                bf16x8 bh = *(const bf16x8*)&wc[kk*32 + ak];
#pragma unroll
                for (int mt = 0; mt < 4; mt++)
                    acc[mt] = MFMA(ao[mt][kk], bh, acc[mt]);
            }
#pragma unroll
            for (int mt = 0; mt < 4; mt++)
#pragma unroll
                for (int rg = 0; rg < 4; rg++) {
                    const int row = mt*16 + rg0 + rg;
                    if (row < NTOK)
                        xattn[((size_t)wid * NTOK + row) * DIMC + col] =
                            f2bf(acc[mt][rg] + bias);
                }
        }
    }
}

// ---------------------------------------------------------------------------
// K2: LN2 + MLP + residual — r9 structure + s_dest table + no tail barrier.
// erff gelu, kk-outer a4 reuse, 51.2 KB LDS, (256,3), VGPR 84 no spill.
// Direct-measured 205 us.
// ---------------------------------------------------------------------------
__global__ __launch_bounds__(256, 3)
void swin_mlp(const u16* __restrict__ xattn,
              const float* __restrict__ g2, const float* __restrict__ be2,
              const float* __restrict__ b1f, const float* __restrict__ b2f,
              const u16* __restrict__ wsw, float* __restrict__ out)
{
    __shared__ __align__(16) u16 s_X[64 * LDA];    // 25.6 KB (xln)
    __shared__ __align__(16) u16 s_H[64 * LDA];    // 25.6 KB (h 192-col chunk)
    __shared__ u32 s_dest[64];                     // per-row out base offsets

    const int tid  = threadIdx.x;
    const int wv   = tid >> 6;
    const int lane = tid & 63;
    const int ar   = lane & 15;
    const int ak   = (lane >> 4) << 3;
    const int rg0  = (lane >> 4) << 2;
    const int base = blockIdx.x * 64;
    const u16* W1t = wsw + OFF_W1;
    const u16* W2t = wsw + OFF_W2;

    // ---- LN2 over 64 token rows + dest-table fill ----
    for (int t = wv; t < 64; t += 4) {
        const u16* src = xattn + (size_t)(base + t) * DIMC;
        float v0 = bf2f(src[lane]);
        float v1 = bf2f(src[lane + 64]);
        float v2 = bf2f(src[lane + 128]);
        float s  = v0 + v1 + v2;
        float s2 = v0*v0 + v1*v1 + v2*v2;
#pragma unroll
        for (int off = 32; off > 0; off >>= 1) {
            s  += __shfl_xor(s,  off);
            s2 += __shfl_xor(s2, off);
        }
        const float mu   = s * (1.f / 192.f);
        const float rstd = rsqrtf(s2 * (1.f / 192.f) - mu * mu + 1e-5f);
        s_X[t*LDA + lane      ] = f2bf((v0-mu)*rstd*g2[lane]     + be2[lane]);
        s_X[t*LDA + lane + 64 ] = f2bf((v1-mu)*rstd*g2[lane+64]  + be2[lane+64]);
        s_X[t*LDA + lane + 128] = f2bf((v2-mu)*rstd*g2[lane+128] + be2[lane+128]);
    }
    if (tid < 64) {
        const int grow = base + tid;
        const int w = grow / 49, t = grow - w * 49;
        const int bb = w >> 6, wi = (w >> 3) & 7, wj = w & 7;
        const int pi = t / 7, pj = t - pi * 7;
        const int di = (wi * WSZ + pi + SSH) % HH;
        const int dj = (wj * WSZ + pj + SSH) % HH;
        s_dest[tid] = (u32)((bb * LTOT + di * HH + dj) * DIMC);
    }
    __syncthreads();

    // ---- MLP: 4 hidden-chunks of 192; accO in regs across chunks ----
    f32x4 accO[3][4];
#pragma unroll
    for (int i = 0; i < 3; i++)
#pragma unroll
        for (int m = 0; m < 4; m++) accO[i][m] = 0;

    for (int cc = 0; cc < 4; cc++) {
        // MLP1 chunk: 3 col-tiles per wave, A-frag reused across tiles per kk
        {
            f32x4 acc1[3][4];
#pragma unroll
            for (int i = 0; i < 3; i++)
#pragma unroll
                for (int m = 0; m < 4; m++) acc1[i][m] = 0;
#pragma unroll
            for (int kk = 0; kk < 6; kk++) {
                bf16x8 a4[4];
#pragma unroll
                for (int mt = 0; mt < 4; mt++)
                    a4[mt] = *(const bf16x8*)&s_X[(mt*16 + ar)*LDA + kk*32 + ak];
#pragma unroll
                for (int ntl = 0; ntl < 3; ntl++) {
                    const int ngl = cc*192 + (wv*3 + ntl)*16 + ar;
                    bf16x8 w = *(const bf16x8*)&W1t[(size_t)ngl * 192 + kk*32 + ak];
#pragma unroll
                    for (int mt = 0; mt < 4; mt++)
                        acc1[ntl][mt] = MFMA(a4[mt], w, acc1[ntl][mt]);
                }
            }
#pragma unroll
            for (int ntl = 0; ntl < 3; ntl++) {
                const int ncol = (wv*3 + ntl)*16 + ar;
                const float bias = b1f[cc*192 + ncol];
#pragma unroll
                for (int mt = 0; mt < 4; mt++)
#pragma unroll
                    for (int rg = 0; rg < 4; rg++) {
                        const float z = acc1[ntl][mt][rg] + bias;
                        const float ge = 0.5f * z * (1.f + erff(z * 0.70710678118654752f));
                        s_H[(mt*16 + rg0 + rg)*LDA + ncol] = f2bf(ge);
                    }
            }
        }
        __syncthreads();
        // MLP2 partial over this 192-wide K chunk (kk-outer, a4 reuse)
        {
#pragma unroll
            for (int kk = 0; kk < 6; kk++) {
                bf16x8 a4[4];
#pragma unroll
                for (int mt = 0; mt < 4; mt++)
                    a4[mt] = *(const bf16x8*)&s_H[(mt*16 + ar)*LDA + kk*32 + ak];
#pragma unroll
                for (int ntl = 0; ntl < 3; ntl++) {
                    const int col = (wv*3 + ntl)*16 + ar;
                    bf16x8 w = *(const bf16x8*)&W2t[(size_t)col * 768 + cc*192 + kk*32 + ak];
#pragma unroll
                    for (int mt = 0; mt < 4; mt++)
                        accO[ntl][mt] = MFMA(a4[mt], w, accO[ntl][mt]);
                }
            }
        }
        if (cc < 3) __syncthreads();   // last chunk: epilogue reads only regs+global
    }

    // ---- epilogue: out = accO + b2 + residual, via dest table ----
#pragma unroll
    for (int ntl = 0; ntl < 3; ntl++) {
        const int col = (wv*3 + ntl)*16 + ar;
        const float bias = b2f[col];
#pragma unroll
        for (int mt = 0; mt < 4; mt++)
#pragma unroll
            for (int rg = 0; rg < 4; rg++) {
                const int row = mt*16 + rg0 + rg;            // block-local
                const size_t grow = (size_t)base + row;
                out[(size_t)s_dest[row] + col] =
                    accO[ntl][mt][rg] + bias + bf2f(xattn[grow * DIMC + col]);
            }
    }
}

// ---------------------------------------------------------------------------
// Fallback: monolithic fused kernel (2 blocks/CU), if ws too small for xattn.
// ---------------------------------------------------------------------------
__global__ __launch_bounds__(256, 2)
void swin_mono(const float* __restrict__ x,
               const float* __restrict__ qkv_b, const float* __restrict__ proj_b,
               const float* __restrict__ g1, const float* __restrict__ be1,
               const float* __restrict__ g2, const float* __restrict__ be2,
               const float* __restrict__ b1f, const float* __restrict__ b2f,
               const u16* __restrict__ wsw, float* __restrict__ out)
{
    __shared__ __align__(16) u16 s_A[64 * LDA];
    __shared__ __align__(16) u16 s_Q[64 * LDA];
    __shared__ __align__(16) u16 s_R3[64 * LDA];

    float* const Sf  = (float*)s_R3;
    u16*  const PU   = s_R3;
    u16*  const Vt   = s_R3 + 64 * LDPU;
    u16*  const s_H  = s_R3;
    u16*  const s_XW = s_Q;

    const int wid = blockIdx.x;
    const int b  = wid >> 6;
    const int wi = (wid >> 3) & 7;
    const int wj = wid & 7;
    const int tid  = threadIdx.x;
    const int wv   = tid >> 6;
    const int lane = tid & 63;
    const int ar   = lane & 15;
    const int ak   = (lane >> 4) << 3;
    const int rg0  = (lane >> 4) << 2;

    const u16* Wpt = wsw + OFF_PW;
    const u16* W1t = wsw + OFF_W1;
    const u16* W2t = wsw + OFF_W2;

    ln1_gather(x, g1, be1, s_A, b, wi, wj, wv, lane);
    __syncthreads();

    attn_all(s_A, s_Q, Sf, PU, Vt, wsw + OFF_QKV, qkv_b, tid, wv, ar, ak, rg0);

    {
        bf16x8 ao[4][6];
#pragma unroll
        for (int mt = 0; mt < 4; mt++)
#pragma unroll
            for (int kk = 0; kk < 6; kk++)
                ao[mt][kk] = *(const bf16x8*)&s_A[(mt*16 + ar)*LDA + kk*32 + ak];
#pragma unroll
        for (int ntl = 0; ntl < 3; ntl++) {
            const int col = (wv*3 + ntl)*16 + ar;
            const float bias = proj_b[col];
            const u16* wc = Wpt + (size_t)col * 192;
            f32x4 acc[4];
#pragma unroll
            for (int mt = 0; mt < 4; mt++) acc[mt] = 0;
#pragma unroll
            for (int kk = 0; kk < 6; kk++) {
                bf16x8 bh = *(const bf16x8*)&wc[kk*32 + ak];
#pragma unroll
                for (int mt = 0; mt < 4; mt++)
                    acc[mt] = MFMA(ao[mt][kk], bh, acc[mt]);
            }
#pragma unroll
            for (int mt = 0; mt < 4; mt++)
#pragma unroll
                for (int rg = 0; rg < 4; rg++)
                    s_XW[(mt*16 + rg0 + rg)*LDA + col] = f2bf(acc[mt][rg] + bias);
        }
    }
    __syncthreads();

    for (int t = wv; t < NTOK; t += 4) {
        float v0 = bf2f(s_XW[t*LDA + lane      ]);
        float v1 = bf2f(s_XW[t*LDA + lane + 64 ]);
        float v2 = bf2f(s_XW[t*LDA + lane + 128]);
        float s  = v0 + v1 + v2;
        float s2 = v0*v0 + v1*v1 + v2*v2;
#pragma unroll
        for (int off = 32; off > 0; off >>= 1) {
            s  += __shfl_xor(s,  off);
            s2 += __shfl_xor(s2, off);
        }
        const float mu   = s * (1.f / 192.f);
        const float rstd = rsqrtf(s2 * (1.f / 192.f) - mu * mu + 1e-5f);
        s_A[t*LDA + lane      ] = f2bf((v0-mu)*rstd*g2[lane]     + be2[lane]);
        s_A[t*LDA + lane + 64 ] = f2bf((v1-mu)*rstd*g2[lane+64]  + be2[lane+64]);
        s_A[t*LDA + lane + 128] = f2bf((v2-mu)*rstd*g2[lane+128] + be2[lane+128]);
    }
    __syncthreads();

    f32x4 accO[3][4];
#pragma unroll
    for (int i = 0; i < 3; i++)
#pragma unroll
        for (int m = 0; m < 4; m++) accO[i][m] = 0;

    for (int cc = 0; cc < 4; cc++) {
        {
            f32x4 acc1[3][4];
#pragma unroll
            for (int i = 0; i < 3; i++)
#pragma unroll
                for (int m = 0; m < 4; m++) acc1[i][m] = 0;
#pragma unroll
            for (int kk = 0; kk < 6; kk++) {
                bf16x8 a4[4];
#pragma unroll
                for (int mt = 0; mt < 4; mt++)
                    a4[mt] = *(const bf16x8*)&s_A[(mt*16 + ar)*LDA + kk*32 + ak];
#pragma unroll
                for (int ntl = 0; ntl < 3; ntl++) {
                    const int ngl = cc*192 + (wv*3 + ntl)*16 + ar;
                    bf16x8 w = *(const bf16x8*)&W1t[(size_t)ngl * 192 + kk*32 + ak];
#pragma unroll
                    for (int mt = 0; mt < 4; mt++)
                        acc1[ntl][mt] = MFMA(a4[mt], w, acc1[ntl][mt]);
                }
            }
#pragma unroll
            for (int ntl = 0; ntl < 3; ntl++) {
                const int ncol = (wv*3 + ntl)*16 + ar;
                const float bias = b1f[cc*192 + ncol];
#pragma unroll
                for (int mt = 0; mt < 4; mt++)
#pragma unroll
                    for (int rg = 0; rg < 4; rg++) {
                        const float z = acc1[ntl][mt][rg] + bias;
                        const float ge = 0.5f * z * (1.f + erff(z * 0.70710678118654752f));
                        s_H[(mt*16 + rg0 + rg)*LDA + ncol] = f2bf(ge);
                    }
            }
        }
        __syncthreads();
        {
#pragma unroll
            for (int kk = 0; kk < 6; kk++) {
                bf16x8 a4[4];
#pragma unroll
                for (int mt = 0; mt < 4; mt++)
                    a4[mt] = *(const bf16x8*)&s_H[(mt*16 + ar)*LDA + kk*32 + ak];
#pragma unroll
                for (int ntl = 0; ntl < 3; ntl++) {
                    const int col = (wv*3 + ntl)*16 + ar;
                    bf16x8 w = *(const bf16x8*)&W2t[(size_t)col * 768 + cc*192 + kk*32 + ak];
#pragma unroll
                    for (int mt = 0; mt < 4; mt++)
                        accO[ntl][mt] = MFMA(a4[mt], w, accO[ntl][mt]);
                }
            }
        }
        __syncthreads();
    }

#pragma unroll
    for (int ntl = 0; ntl < 3; ntl++) {
        const int col = (wv*3 + ntl)*16 + ar;
        const float bias = b2f[col];
#pragma unroll
        for (int mt = 0; mt < 4; mt++)
#pragma unroll
            for (int rg = 0; rg < 4; rg++) {
                const int row = mt*16 + rg0 + rg;
                if (row < NTOK) {
                    const int pi = row / 7, pj = row - pi * 7;
                    const int di = (wi * WSZ + pi + SSH) % HH;
                    const int dj = (wj * WSZ + pj + SSH) % HH;
                    out[((size_t)b * LTOT + di * HH + dj) * DIMC + col] =
                        accO[ntl][mt][rg] + bias + bf2f(s_XW[row*LDA + col]);
                }
            }
    }
}

extern "C" void kernel_launch(void* const* d_in, const int* in_sizes, int n_in,
                              void* d_out, int out_size, void* d_ws, size_t ws_size,
                              hipStream_t stream)
{
    const float* x      = (const float*)d_in[0];
    const float* qkv_w  = (const float*)d_in[1];
    const float* qkv_b  = (const float*)d_in[2];
    const float* proj_w = (const float*)d_in[3];
    const float* proj_b = (const float*)d_in[4];
    const float* g1     = (const float*)d_in[5];
    const float* be1    = (const float*)d_in[6];
    const float* g2     = (const float*)d_in[7];
    const float* be2    = (const float*)d_in[8];
    const float* w1     = (const float*)d_in[9];
    const float* b1     = (const float*)d_in[10];
    const float* w2     = (const float*)d_in[11];
    const float* b2     = (const float*)d_in[12];
    float* out = (float*)d_out;

    cvt_weights<<<256, 256, 0, stream>>>(qkv_w, proj_w, w1, w2, (u16*)d_ws);

    if (ws_size >= (size_t)WS_BYTES + XATTN_BYTES) {
        u16* xattn = (u16*)d_ws + WS_ELEMS;
        swin_attn<<<NWIN_T, 256, 0, stream>>>(x, qkv_b, proj_b, g1, be1,
                                              (const u16*)d_ws, xattn);
        swin_mlp<<<NTOKENS/64, 256, 0, stream>>>(xattn, g2, be2, b1, b2,
                                                 (const u16*)d_ws, out);
    } else {
        swin_mono<<<NWIN_T, 256, 0, stream>>>(x, qkv_b, proj_b, g1, be1, g2, be2,
                                              b1, b2, (const u16*)d_ws, out);
    }
}

// Round 19
// 346.747 us; speedup vs baseline: 1.2644x; 1.0001x over previous
//
#include <hip/hip_runtime.h>

typedef unsigned short u16;
typedef unsigned int   u32;
typedef __attribute__((ext_vector_type(8))) short bf16x8;
typedef __attribute__((ext_vector_type(4))) float f32x4;

#define DIMC   192
#define HH     56
#define WSZ    7
#define SSH    3
#define NTOK   49
#define NWIN_T 2048
#define HIDDEN 768
#define LTOT   3136
#define NTOKENS 100352

#define LDA    200    // u16 row stride, [64][<=192] tiles (400B rows)
#define LDSS   68     // f32 row stride of S
#define LDPU   136    // u16 view (2*LDSS): hi cols 0-63, lo cols 64-127
#define LDVT   72     // u16 row stride of V^T

// ws layout (u16 elems): bf16 W^T[N][K] (hi only; split-P keeps accuracy)
#define OFF_QKV 0                         // 576 cols * 192
#define OFF_PW  110592                    // + 192 * 192
#define OFF_W1  147456                    // + 768 * 192
#define OFF_W2  294912                    // + 192 * 768
#define WS_ELEMS 442368
#define WS_BYTES (WS_ELEMS * 2)
#define XATTN_ELEMS ((size_t)NWIN_T * NTOK * DIMC)
#define XATTN_BYTES (XATTN_ELEMS * 2)                    // 38.5 MB

#define MFMA(a,b,c) __builtin_amdgcn_mfma_f32_16x16x32_bf16((a),(b),(c),0,0,0)

__device__ __forceinline__ float bf2f(u16 u) {
    union { u32 i; float f; } v; v.i = ((u32)u) << 16; return v.f;
}
__device__ __forceinline__ u16 f2bf(float f) {
    union { float ff; u32 i; } v; v.ff = f;
    u32 x = v.i;
    return (u16)((x + 0x7FFFu + ((x >> 16) & 1u)) >> 16);  // RNE
}

// ---------------------------------------------------------------------------
// Prep: fp32 [K][N] weights -> bf16 W^T [N][K] in ws.
// ---------------------------------------------------------------------------
__global__ void cvt_weights(const float* __restrict__ qkv_w,
                            const float* __restrict__ proj_w,
                            const float* __restrict__ w1,
                            const float* __restrict__ w2,
                            u16* __restrict__ ws)
{
    const int idx = blockIdx.x * blockDim.x + threadIdx.x;
    const int stride = gridDim.x * blockDim.x;
    for (int i = idx; i < 110592; i += stride) {        // qkv [192][576]
        int k = i / 576, n = i - k * 576;
        ws[OFF_QKV + n * 192 + k] = f2bf(qkv_w[i]);
    }
    for (int i = idx; i < 36864; i += stride) {         // proj [192][192]
        int k = i / 192, n = i - k * 192;
        ws[OFF_PW + n * 192 + k] = f2bf(proj_w[i]);
    }
    for (int i = idx; i < 147456; i += stride) {        // w1 [192][768]
        int k = i / 768, n = i - k * 768;
        ws[OFF_W1 + n * 192 + k] = f2bf(w1[i]);
    }
    for (int i = idx; i < 147456; i += stride) {        // w2 [768][192]
        int k = i / 192, n = i - k * 192;
        ws[OFF_W2 + n * 768 + k] = f2bf(w2[i]);
    }
}

// ---------------------------------------------------------------------------
// P1: gather (shift -SSH) + LN1 -> s_A [64][192]; pad rows 49..63 zeroed.
// ---------------------------------------------------------------------------
__device__ __forceinline__ void ln1_gather(
    const float* __restrict__ x, const float* __restrict__ g1,
    const float* __restrict__ be1, u16* __restrict__ s_A,
    int b, int wi, int wj, int wv, int lane)
{
    for (int t = wv; t < 64; t += 4) {
        if (t < NTOK) {
            const int pi = t / 7, pj = t - pi * 7;
            const int si = (wi * WSZ + pi + SSH) % HH;
            const int sj = (wj * WSZ + pj + SSH) % HH;
            const float* src = x + ((size_t)b * LTOT + si * HH + sj) * DIMC;
            float v0 = src[lane], v1 = src[lane + 64], v2 = src[lane + 128];
            float s  = v0 + v1 + v2;
            float s2 = v0 * v0 + v1 * v1 + v2 * v2;
#pragma unroll
            for (int off = 32; off > 0; off >>= 1) {
                s  += __shfl_xor(s,  off);
                s2 += __shfl_xor(s2, off);
            }
            const float mu   = s * (1.f / 192.f);
            const float rstd = rsqrtf(s2 * (1.f / 192.f) - mu * mu + 1e-5f);
            s_A[t*LDA + lane      ] = f2bf((v0-mu)*rstd*g1[lane]     + be1[lane]);
            s_A[t*LDA + lane + 64 ] = f2bf((v1-mu)*rstd*g1[lane+64]  + be1[lane+64]);
            s_A[t*LDA + lane + 128] = f2bf((v2-mu)*rstd*g1[lane+128] + be1[lane+128]);
        } else {
            s_A[t*LDA + lane] = 0; s_A[t*LDA + lane + 64] = 0; s_A[t*LDA + lane + 128] = 0;
        }
    }
}

// ---------------------------------------------------------------------------
// attention: xn frags hoisted to regs; 3 QKV groups x 2 heads; MFMA QK^T,
// wave-parallel fp32 softmax, split hi/lo P MFMA PV. O ends in s_A.
// Caller may alias Sf/PU/Vt INTO s_A (xn is register-hoisted; O written only
// after last PV barrier).
// ---------------------------------------------------------------------------
__device__ __forceinline__ void attn_all(
    u16* __restrict__ s_A, u16* __restrict__ s_Q,
    float* Sf, u16* PU, u16* Vt,
    const u16* __restrict__ Wqkvt, const float* __restrict__ qkv_b,
    int tid, int wv, int ar, int ak, int rg0)
{
    const float scale = 0.1767766952966369f;   // 1/sqrt(32)
    f32x4 o[12];

    bf16x8 ax[4][6];
#pragma unroll
    for (int mt = 0; mt < 4; mt++)
#pragma unroll
        for (int kk = 0; kk < 6; kk++)
            ax[mt][kk] = *(const bf16x8*)&s_A[(mt*16 + ar)*LDA + kk*32 + ak];

#pragma unroll
    for (int G = 0; G < 3; G++) {
#pragma unroll
        for (int tl = 0; tl < 3; tl++) {
            const int tt = wv*3 + tl;
            const int section = tt >> 2, idxq = tt & 3;
            const int gcol = section*192 + G*64 + idxq*16 + ar;
            const int lcol = section*64 + idxq*16 + ar;
            const float bias = qkv_b[gcol];
            const u16* wc = Wqkvt + (size_t)gcol * 192;
            f32x4 acc[4];
#pragma unroll
            for (int mt = 0; mt < 4; mt++) acc[mt] = 0;
#pragma unroll
            for (int kk = 0; kk < 6; kk++) {
                bf16x8 bh = *(const bf16x8*)&wc[kk*32 + ak];
#pragma unroll
                for (int mt = 0; mt < 4; mt++)
                    acc[mt] = MFMA(ax[mt][kk], bh, acc[mt]);
            }
#pragma unroll
            for (int mt = 0; mt < 4; mt++)
#pragma unroll
                for (int rg = 0; rg < 4; rg++)
                    s_Q[(mt*16 + rg0 + rg)*LDA + lcol] = f2bf(acc[mt][rg] + bias);
        }
        __syncthreads();

#pragma unroll
        for (int HL = 0; HL < 2; HL++) {
            {
                bf16x8 bk = *(const bf16x8*)&s_Q[(wv*16 + ar)*LDA + 64 + HL*32 + ak];
#pragma unroll
                for (int mt = 0; mt < 4; mt++) {
                    bf16x8 aq = *(const bf16x8*)&s_Q[(mt*16 + ar)*LDA + HL*32 + ak];
                    f32x4 sa; sa = 0;
                    sa = MFMA(aq, bk, sa);
#pragma unroll
                    for (int rg = 0; rg < 4; rg++)
                        Sf[(mt*16 + rg0 + rg)*LDSS + wv*16 + ar] = sa[rg] * scale;
                }
            }
            __syncthreads();
            {
                const int row = tid >> 2, sub = tid & 3;
                if (row < NTOK) {
                    float e[16]; float m = -1e30f;
#pragma unroll
                    for (int i = 0; i < 16; i++) {
                        const int j = sub + 4*i;
                        e[i] = (j < NTOK) ? Sf[row*LDSS + j] : -1e30f;
                        m = fmaxf(m, e[i]);
                    }
                    m = fmaxf(m, __shfl_xor(m, 1));
                    m = fmaxf(m, __shfl_xor(m, 2));
                    float sum = 0.f;
#pragma unroll
                    for (int i = 0; i < 16; i++) { e[i] = __expf(e[i] - m); sum += e[i]; }
                    sum += __shfl_xor(sum, 1);
                    sum += __shfl_xor(sum, 2);
                    const float inv = 1.f / sum;
#pragma unroll
                    for (int i = 0; i < 16; i++) {
                        const int j = sub + 4*i;
                        const float p = e[i] * inv;   // 0 for j>=49 -> pad cols zero
                        const u16 hb = f2bf(p);
                        PU[row*LDPU + j] = hb;
                        PU[row*LDPU + 64 + j] = f2bf(p - bf2f(hb));
                    }
                }
                for (int i2 = tid; i2 < 2048; i2 += 256) {
                    const int d = i2 & 31, j = i2 >> 5;
                    Vt[d*LDVT + j] = (j < NTOK) ? s_Q[j*LDA + 128 + HL*32 + d] : (u16)0;
                }
            }
            __syncthreads();
            {
                const int dcol = (wv & 1)*16 + ar;
                const int mtb = (wv >> 1) << 1;
#pragma unroll
                for (int mi = 0; mi < 2; mi++) {
                    f32x4 accv; accv = 0;
#pragma unroll
                    for (int kk = 0; kk < 2; kk++) {
                        bf16x8 ph = *(const bf16x8*)&PU[((mtb+mi)*16 + ar)*LDPU + kk*32 + ak];
                        bf16x8 pl = *(const bf16x8*)&PU[((mtb+mi)*16 + ar)*LDPU + 64 + kk*32 + ak];
                        bf16x8 bv = *(const bf16x8*)&Vt[dcol*LDVT + kk*32 + ak];
                        accv = MFMA(ph, bv, accv);
                        accv = MFMA(pl, bv, accv);
                    }
                    o[(G*2 + HL)*2 + mi] = accv;
                }
            }
            __syncthreads();
        }
    }

    {
        const int mtb = (wv >> 1) << 1;
        const int cbase = (wv & 1)*16 + ar;
#pragma unroll
        for (int hp = 0; hp < 6; hp++) {
            const int col = hp*32 + cbase;
#pragma unroll
            for (int mi = 0; mi < 2; mi++)
#pragma unroll
                for (int rg = 0; rg < 4; rg++)
                    s_A[((mtb+mi)*16 + rg0 + rg)*LDA + col] = f2bf(o[hp*2 + mi][rg]);
        }
    }
    __syncthreads();
}

// ---------------------------------------------------------------------------
// K1: LN1 + QKV + attention + proj -> xattn. S/P/Vt alias into s_A ->
// 51.2 KB LDS (HW gives 3 blocks/CU); launch_bounds(256,2) keeps regalloc
// free (~128 VGPR, no spill). Direct-measured ~137 us.
// ---------------------------------------------------------------------------
__global__ __launch_bounds__(256, 2)
void swin_attn(const float* __restrict__ x,
               const float* __restrict__ qkv_b, const float* __restrict__ proj_b,
               const float* __restrict__ g1, const float* __restrict__ be1,
               const u16* __restrict__ wsw, u16* __restrict__ xattn)
{
    __shared__ __align__(16) u16 s_A[64 * LDA];                 // 25.6 KB
    __shared__ __align__(16) u16 s_Q[64 * LDA];                 // 25.6 KB

    float* const Sf = (float*)s_A;
    u16*  const PU  = s_A;
    u16*  const Vt  = s_A + 64 * LDPU;

    const int wid = blockIdx.x;
    const int b  = wid >> 6;
    const int wi = (wid >> 3) & 7;
    const int wj = wid & 7;
    const int tid  = threadIdx.x;
    const int wv   = tid >> 6;
    const int lane = tid & 63;
    const int ar   = lane & 15;
    const int ak   = (lane >> 4) << 3;
    const int rg0  = (lane >> 4) << 2;

    ln1_gather(x, g1, be1, s_A, b, wi, wj, wv, lane);
    __syncthreads();

    attn_all(s_A, s_Q, Sf, PU, Vt, wsw + OFF_QKV, qkv_b, tid, wv, ar, ak, rg0);

    // ---- proj: XW = O @ Wp + b -> global xattn (bf16) ----
    {
        const u16* Wpt = wsw + OFF_PW;
        bf16x8 ao[4][6];
#pragma unroll
        for (int mt = 0; mt < 4; mt++)
#pragma unroll
            for (int kk = 0; kk < 6; kk++)
                ao[mt][kk] = *(const bf16x8*)&s_A[(mt*16 + ar)*LDA + kk*32 + ak];
#pragma unroll
        for (int ntl = 0; ntl < 3; ntl++) {
            const int col = (wv*3 + ntl)*16 + ar;
            const float bias = proj_b[col];
            const u16* wc = Wpt + (size_t)col * 192;
            f32x4 acc[4];
#pragma unroll
            for (int mt = 0; mt < 4; mt++) acc[mt] = 0;
#pragma unroll
            for (int kk = 0; kk < 6; kk++) {
                bf16x8 bh = *(const bf16x8*)&wc[kk*32 + ak];
#pragma unroll
                for (int mt = 0; mt < 4; mt++)
                    acc[mt] = MFMA(ao[mt][kk], bh, acc[mt]);
            }
#pragma unroll
            for (int mt = 0; mt < 4; mt++)
#pragma unroll
                for (int rg = 0; rg < 4; rg++) {
                    const int row = mt*16 + rg0 + rg;
                    if (row < NTOK)
                        xattn[((size_t)wid * NTOK + row) * DIMC + col] =
                            f2bf(acc[mt][rg] + bias);
                }
        }
    }
}

// ---------------------------------------------------------------------------
// K2: LN2 + MLP + residual — r9 structure + s_dest table + no tail barrier.
// erff gelu, kk-outer a4 reuse, 51.2 KB LDS, (256,3), VGPR 84 no spill.
// Direct-measured ~205 us.
// ---------------------------------------------------------------------------
__global__ __launch_bounds__(256, 3)
void swin_mlp(const u16* __restrict__ xattn,
              const float* __restrict__ g2, const float* __restrict__ be2,
              const float* __restrict__ b1f, const float* __restrict__ b2f,
              const u16* __restrict__ wsw, float* __restrict__ out)
{
    __shared__ __align__(16) u16 s_X[64 * LDA];    // 25.6 KB (xln)
    __shared__ __align__(16) u16 s_H[64 * LDA];    // 25.6 KB (h 192-col chunk)
    __shared__ u32 s_dest[64];                     // per-row out base offsets

    const int tid  = threadIdx.x;
    const int wv   = tid >> 6;
    const int lane = tid & 63;
    const int ar   = lane & 15;
    const int ak   = (lane >> 4) << 3;
    const int rg0  = (lane >> 4) << 2;
    const int base = blockIdx.x * 64;
    const u16* W1t = wsw + OFF_W1;
    const u16* W2t = wsw + OFF_W2;

    // ---- LN2 over 64 token rows + dest-table fill ----
    for (int t = wv; t < 64; t += 4) {
        const u16* src = xattn + (size_t)(base + t) * DIMC;
        float v0 = bf2f(src[lane]);
        float v1 = bf2f(src[lane + 64]);
        float v2 = bf2f(src[lane + 128]);
        float s  = v0 + v1 + v2;
        float s2 = v0*v0 + v1*v1 + v2*v2;
#pragma unroll
        for (int off = 32; off > 0; off >>= 1) {
            s  += __shfl_xor(s,  off);
            s2 += __shfl_xor(s2, off);
        }
        const float mu   = s * (1.f / 192.f);
        const float rstd = rsqrtf(s2 * (1.f / 192.f) - mu * mu + 1e-5f);
        s_X[t*LDA + lane      ] = f2bf((v0-mu)*rstd*g2[lane]     + be2[lane]);
        s_X[t*LDA + lane + 64 ] = f2bf((v1-mu)*rstd*g2[lane+64]  + be2[lane+64]);
        s_X[t*LDA + lane + 128] = f2bf((v2-mu)*rstd*g2[lane+128] + be2[lane+128]);
    }
    if (tid < 64) {
        const int grow = base + tid;
        const int w = grow / 49, t = grow - w * 49;
        const int bb = w >> 6, wi = (w >> 3) & 7, wj = w & 7;
        const int pi = t / 7, pj = t - pi * 7;
        const int di = (wi * WSZ + pi + SSH) % HH;
        const int dj = (wj * WSZ + pj + SSH) % HH;
        s_dest[tid] = (u32)((bb * LTOT + di * HH + dj) * DIMC);
    }
    __syncthreads();

    // ---- MLP: 4 hidden-chunks of 192; accO in regs across chunks ----
    f32x4 accO[3][4];
#pragma unroll
    for (int i = 0; i < 3; i++)
#pragma unroll
        for (int m = 0; m < 4; m++) accO[i][m] = 0;

    for (int cc = 0; cc < 4; cc++) {
        // MLP1 chunk: 3 col-tiles per wave, A-frag reused across tiles per kk
        {
            f32x4 acc1[3][4];
#pragma unroll
            for (int i = 0; i < 3; i++)
#pragma unroll
                for (int m = 0; m < 4; m++) acc1[i][m] = 0;
#pragma unroll
            for (int kk = 0; kk < 6; kk++) {
                bf16x8 a4[4];
#pragma unroll
                for (int mt = 0; mt < 4; mt++)
                    a4[mt] = *(const bf16x8*)&s_X[(mt*16 + ar)*LDA + kk*32 + ak];
#pragma unroll
                for (int ntl = 0; ntl < 3; ntl++) {
                    const int ngl = cc*192 + (wv*3 + ntl)*16 + ar;
                    bf16x8 w = *(const bf16x8*)&W1t[(size_t)ngl * 192 + kk*32 + ak];
#pragma unroll
                    for (int mt = 0; mt < 4; mt++)
                        acc1[ntl][mt] = MFMA(a4[mt], w, acc1[ntl][mt]);
                }
            }
#pragma unroll
            for (int ntl = 0; ntl < 3; ntl++) {
                const int ncol = (wv*3 + ntl)*16 + ar;
                const float bias = b1f[cc*192 + ncol];
#pragma unroll
                for (int mt = 0; mt < 4; mt++)
#pragma unroll
                    for (int rg = 0; rg < 4; rg++) {
                        const float z = acc1[ntl][mt][rg] + bias;
                        const float ge = 0.5f * z * (1.f + erff(z * 0.70710678118654752f));
                        s_H[(mt*16 + rg0 + rg)*LDA + ncol] = f2bf(ge);
                    }
            }
        }
        __syncthreads();
        // MLP2 partial over this 192-wide K chunk (kk-outer, a4 reuse)
        {
#pragma unroll
            for (int kk = 0; kk < 6; kk++) {
                bf16x8 a4[4];
#pragma unroll
                for (int mt = 0; mt < 4; mt++)
                    a4[mt] = *(const bf16x8*)&s_H[(mt*16 + ar)*LDA + kk*32 + ak];
#pragma unroll
                for (int ntl = 0; ntl < 3; ntl++) {
                    const int col = (wv*3 + ntl)*16 + ar;
                    bf16x8 w = *(const bf16x8*)&W2t[(size_t)col * 768 + cc*192 + kk*32 + ak];
#pragma unroll
                    for (int mt = 0; mt < 4; mt++)
                        accO[ntl][mt] = MFMA(a4[mt], w, accO[ntl][mt]);
                }
            }
        }
        if (cc < 3) __syncthreads();   // last chunk: epilogue reads only regs+global
    }

    // ---- epilogue: out = accO + b2 + residual, via dest table ----
#pragma unroll
    for (int ntl = 0; ntl < 3; ntl++) {
        const int col = (wv*3 + ntl)*16 + ar;
        const float bias = b2f[col];
#pragma unroll
        for (int mt = 0; mt < 4; mt++)
#pragma unroll
            for (int rg = 0; rg < 4; rg++) {
                const int row = mt*16 + rg0 + rg;            // block-local
                const size_t grow = (size_t)base + row;
                out[(size_t)s_dest[row] + col] =
                    accO[ntl][mt][rg] + bias + bf2f(xattn[grow * DIMC + col]);
            }
    }
}

// ---------------------------------------------------------------------------
// Fallback: monolithic fused kernel (2 blocks/CU), if ws too small for xattn.
// ---------------------------------------------------------------------------
__global__ __launch_bounds__(256, 2)
void swin_mono(const float* __restrict__ x,
               const float* __restrict__ qkv_b, const float* __restrict__ proj_b,
               const float* __restrict__ g1, const float* __restrict__ be1,
               const float* __restrict__ g2, const float* __restrict__ be2,
               const float* __restrict__ b1f, const float* __restrict__ b2f,
               const u16* __restrict__ wsw, float* __restrict__ out)
{
    __shared__ __align__(16) u16 s_A[64 * LDA];
    __shared__ __align__(16) u16 s_Q[64 * LDA];
    __shared__ __align__(16) u16 s_R3[64 * LDA];

    float* const Sf  = (float*)s_R3;
    u16*  const PU   = s_R3;
    u16*  const Vt   = s_R3 + 64 * LDPU;
    u16*  const s_H  = s_R3;
    u16*  const s_XW = s_Q;

    const int wid = blockIdx.x;
    const int b  = wid >> 6;
    const int wi = (wid >> 3) & 7;
    const int wj = wid & 7;
    const int tid  = threadIdx.x;
    const int wv   = tid >> 6;
    const int lane = tid & 63;
    const int ar   = lane & 15;
    const int ak   = (lane >> 4) << 3;
    const int rg0  = (lane >> 4) << 2;

    const u16* Wpt = wsw + OFF_PW;
    const u16* W1t = wsw + OFF_W1;
    const u16* W2t = wsw + OFF_W2;

    ln1_gather(x, g1, be1, s_A, b, wi, wj, wv, lane);
    __syncthreads();

    attn_all(s_A, s_Q, Sf, PU, Vt, wsw + OFF_QKV, qkv_b, tid, wv, ar, ak, rg0);

    {
        bf16x8 ao[4][6];
#pragma unroll
        for (int mt = 0; mt < 4; mt++)
#pragma unroll
            for (int kk = 0; kk < 6; kk++)
                ao[mt][kk] = *(const bf16x8*)&s_A[(mt*16 + ar)*LDA + kk*32 + ak];
#pragma unroll
        for (int ntl = 0; ntl < 3; ntl++) {
            const int col = (wv*3 + ntl)*16 + ar;
            const float bias = proj_b[col];
            const u16* wc = Wpt + (size_t)col * 192;
            f32x4 acc[4];
#pragma unroll
            for (int mt = 0; mt < 4; mt++) acc[mt] = 0;
#pragma unroll
            for (int kk = 0; kk < 6; kk++) {
                bf16x8 bh = *(const bf16x8*)&wc[kk*32 + ak];
#pragma unroll
                for (int mt = 0; mt < 4; mt++)
                    acc[mt] = MFMA(ao[mt][kk], bh, acc[mt]);
            }
#pragma unroll
            for (int mt = 0; mt < 4; mt++)
#pragma unroll
                for (int rg = 0; rg < 4; rg++)
                    s_XW[(mt*16 + rg0 + rg)*LDA + col] = f2bf(acc[mt][rg] + bias);
        }
    }
    __syncthreads();

    for (int t = wv; t < NTOK; t += 4) {
        float v0 = bf2f(s_XW[t*LDA + lane      ]);
        float v1 = bf2f(s_XW[t*LDA + lane + 64 ]);
        float v2 = bf2f(s_XW[t*LDA + lane + 128]);
        float s  = v0 + v1 + v2;
        float s2 = v0*v0 + v1*v1 + v2*v2;
#pragma unroll
        for (int off = 32; off > 0; off >>= 1) {
            s  += __shfl_xor(s,  off);
            s2 += __shfl_xor(s2, off);
        }
        const float mu   = s * (1.f / 192.f);
        const float rstd = rsqrtf(s2 * (1.f / 192.f) - mu * mu + 1e-5f);
        s_A[t*LDA + lane      ] = f2bf((v0-mu)*rstd*g2[lane]     + be2[lane]);
        s_A[t*LDA + lane + 64 ] = f2bf((v1-mu)*rstd*g2[lane+64]  + be2[lane+64]);
        s_A[t*LDA + lane + 128] = f2bf((v2-mu)*rstd*g2[lane+128] + be2[lane+128]);
    }
    __syncthreads();

    f32x4 accO[3][4];
#pragma unroll
    for (int i = 0; i < 3; i++)
#pragma unroll
        for (int m = 0; m < 4; m++) accO[i][m] = 0;

    for (int cc = 0; cc < 4; cc++) {
        {
            f32x4 acc1[3][4];
#pragma unroll
            for (int i = 0; i < 3; i++)
#pragma unroll
                for (int m = 0; m < 4; m++) acc1[i][m] = 0;
#pragma unroll
            for (int kk = 0; kk < 6; kk++) {
                bf16x8 a4[4];
#pragma unroll
                for (int mt = 0; mt < 4; mt++)
                    a4[mt] = *(const bf16x8*)&s_A[(mt*16 + ar)*LDA + kk*32 + ak];
#pragma unroll
                for (int ntl = 0; ntl < 3; ntl++) {
                    const int ngl = cc*192 + (wv*3 + ntl)*16 + ar;
                    bf16x8 w = *(const bf16x8*)&W1t[(size_t)ngl * 192 + kk*32 + ak];
#pragma unroll
                    for (int mt = 0; mt < 4; mt++)
                        acc1[ntl][mt] = MFMA(a4[mt], w, acc1[ntl][mt]);
                }
            }
#pragma unroll
            for (int ntl = 0; ntl < 3; ntl++) {
                const int ncol = (wv*3 + ntl)*16 + ar;
                const float bias = b1f[cc*192 + ncol];
#pragma unroll
                for (int mt = 0; mt < 4; mt++)
#pragma unroll
                    for (int rg = 0; rg < 4; rg++) {
                        const float z = acc1[ntl][mt][rg] + bias;
                        const float ge = 0.5f * z * (1.f + erff(z * 0.70710678118654752f));
                        s_H[(mt*16 + rg0 + rg)*LDA + ncol] = f2bf(ge);
                    }
            }
        }
        __syncthreads();
        {
#pragma unroll
            for (int kk = 0; kk < 6; kk++) {
                bf16x8 a4[4];
#pragma unroll
                for (int mt = 0; mt < 4; mt++)
                    a4[mt] = *(const bf16x8*)&s_H[(mt*16 + ar)*LDA + kk*32 + ak];
#pragma unroll
                for (int ntl = 0; ntl < 3; ntl++) {
                    const int col = (wv*3 + ntl)*16 + ar;
                    bf16x8 w = *(const bf16x8*)&W2t[(size_t)col * 768 + cc*192 + kk*32 + ak];
#pragma unroll
                    for (int mt = 0; mt < 4; mt++)
                        accO[ntl][mt] = MFMA(a4[mt], w, accO[ntl][mt]);
                }
            }
        }
        __syncthreads();
    }

#pragma unroll
    for (int ntl = 0; ntl < 3; ntl++) {
        const int col = (wv*3 + ntl)*16 + ar;
        const float bias = b2f[col];
#pragma unroll
        for (int mt = 0; mt < 4; mt++)
#pragma unroll
            for (int rg = 0; rg < 4; rg++) {
                const int row = mt*16 + rg0 + rg;
                if (row < NTOK) {
                    const int pi = row / 7, pj = row - pi * 7;
                    const int di = (wi * WSZ + pi + SSH) % HH;
                    const int dj = (wj * WSZ + pj + SSH) % HH;
                    out[((size_t)b * LTOT + di * HH + dj) * DIMC + col] =
                        accO[ntl][mt][rg] + bias + bf2f(s_XW[row*LDA + col]);
                }
            }
    }
}

extern "C" void kernel_launch(void* const* d_in, const int* in_sizes, int n_in,
                              void* d_out, int out_size, void* d_ws, size_t ws_size,
                              hipStream_t stream)
{
    const float* x      = (const float*)d_in[0];
    const float* qkv_w  = (const float*)d_in[1];
    const float* qkv_b  = (const float*)d_in[2];
    const float* proj_w = (const float*)d_in[3];
    const float* proj_b = (const float*)d_in[4];
    const float* g1     = (const float*)d_in[5];
    const float* be1    = (const float*)d_in[6];
    const float* g2     = (const float*)d_in[7];
    const float* be2    = (const float*)d_in[8];
    const float* w1     = (const float*)d_in[9];
    const float* b1     = (const float*)d_in[10];
    const float* w2     = (const float*)d_in[11];
    const float* b2     = (const float*)d_in[12];
    float* out = (float*)d_out;

    cvt_weights<<<256, 256, 0, stream>>>(qkv_w, proj_w, w1, w2, (u16*)d_ws);

    if (ws_size >= (size_t)WS_BYTES + XATTN_BYTES) {
        u16* xattn = (u16*)d_ws + WS_ELEMS;
        swin_attn<<<NWIN_T, 256, 0, stream>>>(x, qkv_b, proj_b, g1, be1,
                                              (const u16*)d_ws, xattn);
        swin_mlp<<<NTOKENS/64, 256, 0, stream>>>(xattn, g2, be2, b1, b2,
                                                 (const u16*)d_ws, out);
    } else {
        swin_mono<<<NWIN_T, 256, 0, stream>>>(x, qkv_b, proj_b, g1, be1, g2, be2,
                                              b1, b2, (const u16*)d_ws, out);
    }
}

// Round 20
// 346.413 us; speedup vs baseline: 1.2657x; 1.0010x over previous
//
#include <hip/hip_runtime.h>

typedef unsigned short u16;
typedef unsigned int   u32;
typedef __attribute__((ext_vector_type(8))) short bf16x8;
typedef __attribute__((ext_vector_type(4))) float f32x4;

#define DIMC   192
#define HH     56
#define WSZ    7
#define SSH    3
#define NTOK   49
#define NWIN_T 2048
#define HIDDEN 768
#define LTOT   3136
#define NTOKENS 100352

#define LDA    200    // u16 row stride, [64][<=192] tiles (400B rows)
#define LDSS   68     // f32 row stride of S
#define LDPU   136    // u16 view (2*LDSS): hi cols 0-63, lo cols 64-127
#define LDVT   72     // u16 row stride of V^T

// ws layout (u16 elems): bf16 W^T[N][K] (hi only; split-P keeps accuracy)
#define OFF_QKV 0                         // 576 cols * 192
#define OFF_PW  110592                    // + 192 * 192
#define OFF_W1  147456                    // + 768 * 192
#define OFF_W2  294912                    // + 192 * 768
#define WS_ELEMS 442368
#define WS_BYTES (WS_ELEMS * 2)
#define XATTN_ELEMS ((size_t)NWIN_T * NTOK * DIMC)
#define XATTN_BYTES (XATTN_ELEMS * 2)                    // 38.5 MB

#define MFMA(a,b,c) __builtin_amdgcn_mfma_f32_16x16x32_bf16((a),(b),(c),0,0,0)

__device__ __forceinline__ float bf2f(u16 u) {
    union { u32 i; float f; } v; v.i = ((u32)u) << 16; return v.f;
}
__device__ __forceinline__ u16 f2bf(float f) {
    union { float ff; u32 i; } v; v.ff = f;
    u32 x = v.i;
    return (u16)((x + 0x7FFFu + ((x >> 16) & 1u)) >> 16);  // RNE
}

// ---------------------------------------------------------------------------
// Prep: fp32 [K][N] weights -> bf16 W^T [N][K] in ws.
// ---------------------------------------------------------------------------
__global__ void cvt_weights(const float* __restrict__ qkv_w,
                            const float* __restrict__ proj_w,
                            const float* __restrict__ w1,
                            const float* __restrict__ w2,
                            u16* __restrict__ ws)
{
    const int idx = blockIdx.x * blockDim.x + threadIdx.x;
    const int stride = gridDim.x * blockDim.x;
    for (int i = idx; i < 110592; i += stride) {        // qkv [192][576]
        int k = i / 576, n = i - k * 576;
        ws[OFF_QKV + n * 192 + k] = f2bf(qkv_w[i]);
    }
    for (int i = idx; i < 36864; i += stride) {         // proj [192][192]
        int k = i / 192, n = i - k * 192;
        ws[OFF_PW + n * 192 + k] = f2bf(proj_w[i]);
    }
    for (int i = idx; i < 147456; i += stride) {        // w1 [192][768]
        int k = i / 768, n = i - k * 768;
        ws[OFF_W1 + n * 192 + k] = f2bf(w1[i]);
    }
    for (int i = idx; i < 147456; i += stride) {        // w2 [768][192]
        int k = i / 192, n = i - k * 192;
        ws[OFF_W2 + n * 768 + k] = f2bf(w2[i]);
    }
}

// ---------------------------------------------------------------------------
// P1: gather (shift -SSH) + LN1 -> s_A [64][192]; pad rows 49..63 zeroed.
// ---------------------------------------------------------------------------
__device__ __forceinline__ void ln1_gather(
    const float* __restrict__ x, const float* __restrict__ g1,
    const float* __restrict__ be1, u16* __restrict__ s_A,
    int b, int wi, int wj, int wv, int lane)
{
    for (int t = wv; t < 64; t += 4) {
        if (t < NTOK) {
            const int pi = t / 7, pj = t - pi * 7;
            const int si = (wi * WSZ + pi + SSH) % HH;
            const int sj = (wj * WSZ + pj + SSH) % HH;
            const float* src = x + ((size_t)b * LTOT + si * HH + sj) * DIMC;
            float v0 = src[lane], v1 = src[lane + 64], v2 = src[lane + 128];
            float s  = v0 + v1 + v2;
            float s2 = v0 * v0 + v1 * v1 + v2 * v2;
#pragma unroll
            for (int off = 32; off > 0; off >>= 1) {
                s  += __shfl_xor(s,  off);
                s2 += __shfl_xor(s2, off);
            }
            const float mu   = s * (1.f / 192.f);
            const float rstd = rsqrtf(s2 * (1.f / 192.f) - mu * mu + 1e-5f);
            s_A[t*LDA + lane      ] = f2bf((v0-mu)*rstd*g1[lane]     + be1[lane]);
            s_A[t*LDA + lane + 64 ] = f2bf((v1-mu)*rstd*g1[lane+64]  + be1[lane+64]);
            s_A[t*LDA + lane + 128] = f2bf((v2-mu)*rstd*g1[lane+128] + be1[lane+128]);
        } else {
            s_A[t*LDA + lane] = 0; s_A[t*LDA + lane + 64] = 0; s_A[t*LDA + lane + 128] = 0;
        }
    }
}

// ---------------------------------------------------------------------------
// attention: xn frags hoisted to regs; 3 QKV groups x 2 heads; MFMA QK^T,
// wave-parallel fp32 softmax, split hi/lo P MFMA PV. O ends in s_A.
// Caller may alias Sf/PU/Vt INTO s_A (xn is register-hoisted; O written only
// after last PV barrier).
// ---------------------------------------------------------------------------
__device__ __forceinline__ void attn_all(
    u16* __restrict__ s_A, u16* __restrict__ s_Q,
    float* Sf, u16* PU, u16* Vt,
    const u16* __restrict__ Wqkvt, const float* __restrict__ qkv_b,
    int tid, int wv, int ar, int ak, int rg0)
{
    const float scale = 0.1767766952966369f;   // 1/sqrt(32)
    f32x4 o[12];

    bf16x8 ax[4][6];
#pragma unroll
    for (int mt = 0; mt < 4; mt++)
#pragma unroll
        for (int kk = 0; kk < 6; kk++)
            ax[mt][kk] = *(const bf16x8*)&s_A[(mt*16 + ar)*LDA + kk*32 + ak];

#pragma unroll
    for (int G = 0; G < 3; G++) {
#pragma unroll
        for (int tl = 0; tl < 3; tl++) {
            const int tt = wv*3 + tl;
            const int section = tt >> 2, idxq = tt & 3;
            const int gcol = section*192 + G*64 + idxq*16 + ar;
            const int lcol = section*64 + idxq*16 + ar;
            const float bias = qkv_b[gcol];
            const u16* wc = Wqkvt + (size_t)gcol * 192;
            f32x4 acc[4];
#pragma unroll
            for (int mt = 0; mt < 4; mt++) acc[mt] = 0;
#pragma unroll
            for (int kk = 0; kk < 6; kk++) {
                bf16x8 bh = *(const bf16x8*)&wc[kk*32 + ak];
#pragma unroll
                for (int mt = 0; mt < 4; mt++)
                    acc[mt] = MFMA(ax[mt][kk], bh, acc[mt]);
            }
#pragma unroll
            for (int mt = 0; mt < 4; mt++)
#pragma unroll
                for (int rg = 0; rg < 4; rg++)
                    s_Q[(mt*16 + rg0 + rg)*LDA + lcol] = f2bf(acc[mt][rg] + bias);
        }
        __syncthreads();

#pragma unroll
        for (int HL = 0; HL < 2; HL++) {
            {
                bf16x8 bk = *(const bf16x8*)&s_Q[(wv*16 + ar)*LDA + 64 + HL*32 + ak];
#pragma unroll
                for (int mt = 0; mt < 4; mt++) {
                    bf16x8 aq = *(const bf16x8*)&s_Q[(mt*16 + ar)*LDA + HL*32 + ak];
                    f32x4 sa; sa = 0;
                    sa = MFMA(aq, bk, sa);
#pragma unroll
                    for (int rg = 0; rg < 4; rg++)
                        Sf[(mt*16 + rg0 + rg)*LDSS + wv*16 + ar] = sa[rg] * scale;
                }
            }
            __syncthreads();
            {
                const int row = tid >> 2, sub = tid & 3;
                if (row < NTOK) {
                    float e[16]; float m = -1e30f;
#pragma unroll
                    for (int i = 0; i < 16; i++) {
                        const int j = sub + 4*i;
                        e[i] = (j < NTOK) ? Sf[row*LDSS + j] : -1e30f;
                        m = fmaxf(m, e[i]);
                    }
                    m = fmaxf(m, __shfl_xor(m, 1));
                    m = fmaxf(m, __shfl_xor(m, 2));
                    float sum = 0.f;
#pragma unroll
                    for (int i = 0; i < 16; i++) { e[i] = __expf(e[i] - m); sum += e[i]; }
                    sum += __shfl_xor(sum, 1);
                    sum += __shfl_xor(sum, 2);
                    const float inv = 1.f / sum;
#pragma unroll
                    for (int i = 0; i < 16; i++) {
                        const int j = sub + 4*i;
                        const float p = e[i] * inv;   // 0 for j>=49 -> pad cols zero
                        const u16 hb = f2bf(p);
                        PU[row*LDPU + j] = hb;
                        PU[row*LDPU + 64 + j] = f2bf(p - bf2f(hb));
                    }
                }
                for (int i2 = tid; i2 < 2048; i2 += 256) {
                    const int d = i2 & 31, j = i2 >> 5;
                    Vt[d*LDVT + j] = (j < NTOK) ? s_Q[j*LDA + 128 + HL*32 + d] : (u16)0;
                }
            }
            __syncthreads();
            {
                const int dcol = (wv & 1)*16 + ar;
                const int mtb = (wv >> 1) << 1;
#pragma unroll
                for (int mi = 0; mi < 2; mi++) {
                    f32x4 accv; accv = 0;
#pragma unroll
                    for (int kk = 0; kk < 2; kk++) {
                        bf16x8 ph = *(const bf16x8*)&PU[((mtb+mi)*16 + ar)*LDPU + kk*32 + ak];
                        bf16x8 pl = *(const bf16x8*)&PU[((mtb+mi)*16 + ar)*LDPU + 64 + kk*32 + ak];
                        bf16x8 bv = *(const bf16x8*)&Vt[dcol*LDVT + kk*32 + ak];
                        accv = MFMA(ph, bv, accv);
                        accv = MFMA(pl, bv, accv);
                    }
                    o[(G*2 + HL)*2 + mi] = accv;
                }
            }
            __syncthreads();
        }
    }

    {
        const int mtb = (wv >> 1) << 1;
        const int cbase = (wv & 1)*16 + ar;
#pragma unroll
        for (int hp = 0; hp < 6; hp++) {
            const int col = hp*32 + cbase;
#pragma unroll
            for (int mi = 0; mi < 2; mi++)
#pragma unroll
                for (int rg = 0; rg < 4; rg++)
                    s_A[((mtb+mi)*16 + rg0 + rg)*LDA + col] = f2bf(o[hp*2 + mi][rg]);
        }
    }
    __syncthreads();
}

// ---------------------------------------------------------------------------
// K1: LN1 + QKV + attention + proj -> xattn. S/P/Vt alias into s_A ->
// 51.2 KB LDS (HW gives 3 blocks/CU); launch_bounds(256,2) keeps regalloc
// free (~128 VGPR, no spill). Direct-measured ~137 us.
// ---------------------------------------------------------------------------
__global__ __launch_bounds__(256, 2)
void swin_attn(const float* __restrict__ x,
               const float* __restrict__ qkv_b, const float* __restrict__ proj_b,
               const float* __restrict__ g1, const float* __restrict__ be1,
               const u16* __restrict__ wsw, u16* __restrict__ xattn)
{
    __shared__ __align__(16) u16 s_A[64 * LDA];                 // 25.6 KB
    __shared__ __align__(16) u16 s_Q[64 * LDA];                 // 25.6 KB

    float* const Sf = (float*)s_A;
    u16*  const PU  = s_A;
    u16*  const Vt  = s_A + 64 * LDPU;

    const int wid = blockIdx.x;
    const int b  = wid >> 6;
    const int wi = (wid >> 3) & 7;
    const int wj = wid & 7;
    const int tid  = threadIdx.x;
    const int wv   = tid >> 6;
    const int lane = tid & 63;
    const int ar   = lane & 15;
    const int ak   = (lane >> 4) << 3;
    const int rg0  = (lane >> 4) << 2;

    ln1_gather(x, g1, be1, s_A, b, wi, wj, wv, lane);
    __syncthreads();

    attn_all(s_A, s_Q, Sf, PU, Vt, wsw + OFF_QKV, qkv_b, tid, wv, ar, ak, rg0);

    // ---- proj: XW = O @ Wp + b -> global xattn (bf16) ----
    {
        const u16* Wpt = wsw + OFF_PW;
        bf16x8 ao[4][6];
#pragma unroll
        for (int mt = 0; mt < 4; mt++)
#pragma unroll
            for (int kk = 0; kk < 6; kk++)
                ao[mt][kk] = *(const bf16x8*)&s_A[(mt*16 + ar)*LDA + kk*32 + ak];
#pragma unroll
        for (int ntl = 0; ntl < 3; ntl++) {
            const int col = (wv*3 + ntl)*16 + ar;
            const float bias = proj_b[col];
            const u16* wc = Wpt + (size_t)col * 192;
            f32x4 acc[4];
#pragma unroll
            for (int mt = 0; mt < 4; mt++) acc[mt] = 0;
#pragma unroll
            for (int kk = 0; kk < 6; kk++) {
                bf16x8 bh = *(const bf16x8*)&wc[kk*32 + ak];
#pragma unroll
                for (int mt = 0; mt < 4; mt++)
                    acc[mt] = MFMA(ao[mt][kk], bh, acc[mt]);
            }
#pragma unroll
            for (int mt = 0; mt < 4; mt++)
#pragma unroll
                for (int rg = 0; rg < 4; rg++) {
                    const int row = mt*16 + rg0 + rg;
                    if (row < NTOK)
                        xattn[((size_t)wid * NTOK + row) * DIMC + col] =
                            f2bf(acc[mt][rg] + bias);
                }
        }
    }
}

// ---------------------------------------------------------------------------
// K2: LN2 + MLP + residual — r9 structure + s_dest table + no tail barrier.
// erff gelu, kk-outer a4 reuse, 51.2 KB LDS, (256,3), VGPR 84 no spill.
// Direct-measured ~204 us.
// ---------------------------------------------------------------------------
__global__ __launch_bounds__(256, 3)
void swin_mlp(const u16* __restrict__ xattn,
              const float* __restrict__ g2, const float* __restrict__ be2,
              const float* __restrict__ b1f, const float* __restrict__ b2f,
              const u16* __restrict__ wsw, float* __restrict__ out)
{
    __shared__ __align__(16) u16 s_X[64 * LDA];    // 25.6 KB (xln)
    __shared__ __align__(16) u16 s_H[64 * LDA];    // 25.6 KB (h 192-col chunk)
    __shared__ u32 s_dest[64];                     // per-row out base offsets

    const int tid  = threadIdx.x;
    const int wv   = tid >> 6;
    const int lane = tid & 63;
    const int ar   = lane & 15;
    const int ak   = (lane >> 4) << 3;
    const int rg0  = (lane >> 4) << 2;
    const int base = blockIdx.x * 64;
    const u16* W1t = wsw + OFF_W1;
    const u16* W2t = wsw + OFF_W2;

    // ---- LN2 over 64 token rows + dest-table fill ----
    for (int t = wv; t < 64; t += 4) {
        const u16* src = xattn + (size_t)(base + t) * DIMC;
        float v0 = bf2f(src[lane]);
        float v1 = bf2f(src[lane + 64]);
        float v2 = bf2f(src[lane + 128]);
        float s  = v0 + v1 + v2;
        float s2 = v0*v0 + v1*v1 + v2*v2;
#pragma unroll
        for (int off = 32; off > 0; off >>= 1) {
            s  += __shfl_xor(s,  off);
            s2 += __shfl_xor(s2, off);
        }
        const float mu   = s * (1.f / 192.f);
        const float rstd = rsqrtf(s2 * (1.f / 192.f) - mu * mu + 1e-5f);
        s_X[t*LDA + lane      ] = f2bf((v0-mu)*rstd*g2[lane]     + be2[lane]);
        s_X[t*LDA + lane + 64 ] = f2bf((v1-mu)*rstd*g2[lane+64]  + be2[lane+64]);
        s_X[t*LDA + lane + 128] = f2bf((v2-mu)*rstd*g2[lane+128] + be2[lane+128]);
    }
    if (tid < 64) {
        const int grow = base + tid;
        const int w = grow / 49, t = grow - w * 49;
        const int bb = w >> 6, wi = (w >> 3) & 7, wj = w & 7;
        const int pi = t / 7, pj = t - pi * 7;
        const int di = (wi * WSZ + pi + SSH) % HH;
        const int dj = (wj * WSZ + pj + SSH) % HH;
        s_dest[tid] = (u32)((bb * LTOT + di * HH + dj) * DIMC);
    }
    __syncthreads();

    // ---- MLP: 4 hidden-chunks of 192; accO in regs across chunks ----
    f32x4 accO[3][4];
#pragma unroll
    for (int i = 0; i < 3; i++)
#pragma unroll
        for (int m = 0; m < 4; m++) accO[i][m] = 0;

    for (int cc = 0; cc < 4; cc++) {
        // MLP1 chunk: 3 col-tiles per wave, A-frag reused across tiles per kk
        {
            f32x4 acc1[3][4];
#pragma unroll
            for (int i = 0; i < 3; i++)
#pragma unroll
                for (int m = 0; m < 4; m++) acc1[i][m] = 0;
#pragma unroll
            for (int kk = 0; kk < 6; kk++) {
                bf16x8 a4[4];
#pragma unroll
                for (int mt = 0; mt < 4; mt++)
                    a4[mt] = *(const bf16x8*)&s_X[(mt*16 + ar)*LDA + kk*32 + ak];
#pragma unroll
                for (int ntl = 0; ntl < 3; ntl++) {
                    const int ngl = cc*192 + (wv*3 + ntl)*16 + ar;
                    bf16x8 w = *(const bf16x8*)&W1t[(size_t)ngl * 192 + kk*32 + ak];
#pragma unroll
                    for (int mt = 0; mt < 4; mt++)
                        acc1[ntl][mt] = MFMA(a4[mt], w, acc1[ntl][mt]);
                }
            }
#pragma unroll
            for (int ntl = 0; ntl < 3; ntl++) {
                const int ncol = (wv*3 + ntl)*16 + ar;
                const float bias = b1f[cc*192 + ncol];
#pragma unroll
                for (int mt = 0; mt < 4; mt++)
#pragma unroll
                    for (int rg = 0; rg < 4; rg++) {
                        const float z = acc1[ntl][mt][rg] + bias;
                        const float ge = 0.5f * z * (1.f + erff(z * 0.70710678118654752f));
                        s_H[(mt*16 + rg0 + rg)*LDA + ncol] = f2bf(ge);
                    }
            }
        }
        __syncthreads();
        // MLP2 partial over this 192-wide K chunk (kk-outer, a4 reuse)
        {
#pragma unroll
            for (int kk = 0; kk < 6; kk++) {
                bf16x8 a4[4];
#pragma unroll
                for (int mt = 0; mt < 4; mt++)
                    a4[mt] = *(const bf16x8*)&s_H[(mt*16 + ar)*LDA + kk*32 + ak];
#pragma unroll
                for (int ntl = 0; ntl < 3; ntl++) {
                    const int col = (wv*3 + ntl)*16 + ar;
                    bf16x8 w = *(const bf16x8*)&W2t[(size_t)col * 768 + cc*192 + kk*32 + ak];
#pragma unroll
                    for (int mt = 0; mt < 4; mt++)
                        accO[ntl][mt] = MFMA(a4[mt], w, accO[ntl][mt]);
                }
            }
        }
        if (cc < 3) __syncthreads();   // last chunk: epilogue reads only regs+global
    }

    // ---- epilogue: out = accO + b2 + residual, via dest table ----
#pragma unroll
    for (int ntl = 0; ntl < 3; ntl++) {
        const int col = (wv*3 + ntl)*16 + ar;
        const float bias = b2f[col];
#pragma unroll
        for (int mt = 0; mt < 4; mt++)
#pragma unroll
            for (int rg = 0; rg < 4; rg++) {
                const int row = mt*16 + rg0 + rg;            // block-local
                const size_t grow = (size_t)base + row;
                out[(size_t)s_dest[row] + col] =
                    accO[ntl][mt][rg] + bias + bf2f(xattn[grow * DIMC + col]);
            }
    }
}

// ---------------------------------------------------------------------------
// Fallback: monolithic fused kernel (2 blocks/CU), if ws too small for xattn.
// ---------------------------------------------------------------------------
__global__ __launch_bounds__(256, 2)
void swin_mono(const float* __restrict__ x,
               const float* __restrict__ qkv_b, const float* __restrict__ proj_b,
               const float* __restrict__ g1, const float* __restrict__ be1,
               const float* __restrict__ g2, const float* __restrict__ be2,
               const float* __restrict__ b1f, const float* __restrict__ b2f,
               const u16* __restrict__ wsw, float* __restrict__ out)
{
    __shared__ __align__(16) u16 s_A[64 * LDA];
    __shared__ __align__(16) u16 s_Q[64 * LDA];
    __shared__ __align__(16) u16 s_R3[64 * LDA];

    float* const Sf  = (float*)s_R3;
    u16*  const PU   = s_R3;
    u16*  const Vt   = s_R3 + 64 * LDPU;
    u16*  const s_H  = s_R3;
    u16*  const s_XW = s_Q;

    const int wid = blockIdx.x;
    const int b  = wid >> 6;
    const int wi = (wid >> 3) & 7;
    const int wj = wid & 7;
    const int tid  = threadIdx.x;
    const int wv   = tid >> 6;
    const int lane = tid & 63;
    const int ar   = lane & 15;
    const int ak   = (lane >> 4) << 3;
    const int rg0  = (lane >> 4) << 2;

    const u16* Wpt = wsw + OFF_PW;
    const u16* W1t = wsw + OFF_W1;
    const u16* W2t = wsw + OFF_W2;

    ln1_gather(x, g1, be1, s_A, b, wi, wj, wv, lane);
    __syncthreads();

    attn_all(s_A, s_Q, Sf, PU, Vt, wsw + OFF_QKV, qkv_b, tid, wv, ar, ak, rg0);

    {
        bf16x8 ao[4][6];
#pragma unroll
        for (int mt = 0; mt < 4; mt++)
#pragma unroll
            for (int kk = 0; kk < 6; kk++)
                ao[mt][kk] = *(const bf16x8*)&s_A[(mt*16 + ar)*LDA + kk*32 + ak];
#pragma unroll
        for (int ntl = 0; ntl < 3; ntl++) {
            const int col = (wv*3 + ntl)*16 + ar;
            const float bias = proj_b[col];
            const u16* wc = Wpt + (size_t)col * 192;
            f32x4 acc[4];
#pragma unroll
            for (int mt = 0; mt < 4; mt++) acc[mt] = 0;
#pragma unroll
            for (int kk = 0; kk < 6; kk++) {
                bf16x8 bh = *(const bf16x8*)&wc[kk*32 + ak];
#pragma unroll
                for (int mt = 0; mt < 4; mt++)
                    acc[mt] = MFMA(ao[mt][kk], bh, acc[mt]);
            }
#pragma unroll
            for (int mt = 0; mt < 4; mt++)
#pragma unroll
                for (int rg = 0; rg < 4; rg++)
                    s_XW[(mt*16 + rg0 + rg)*LDA + col] = f2bf(acc[mt][rg] + bias);
        }
    }
    __syncthreads();

    for (int t = wv; t < NTOK; t += 4) {
        float v0 = bf2f(s_XW[t*LDA + lane      ]);
        float v1 = bf2f(s_XW[t*LDA + lane + 64 ]);
        float v2 = bf2f(s_XW[t*LDA + lane + 128]);
        float s  = v0 + v1 + v2;
        float s2 = v0*v0 + v1*v1 + v2*v2;
#pragma unroll
        for (int off = 32; off > 0; off >>= 1) {
            s  += __shfl_xor(s,  off);
            s2 += __shfl_xor(s2, off);
        }
        const float mu   = s * (1.f / 192.f);
        const float rstd = rsqrtf(s2 * (1.f / 192.f) - mu * mu + 1e-5f);
        s_A[t*LDA + lane      ] = f2bf((v0-mu)*rstd*g2[lane]     + be2[lane]);
        s_A[t*LDA + lane + 64 ] = f2bf((v1-mu)*rstd*g2[lane+64]  + be2[lane+64]);
        s_A[t*LDA + lane + 128] = f2bf((v2-mu)*rstd*g2[lane+128] + be2[lane+128]);
    }
    __syncthreads();

    f32x4 accO[3][4];
#pragma unroll
    for (int i = 0; i < 3; i++)
#pragma unroll
        for (int m = 0; m < 4; m++) accO[i][m] = 0;

    for (int cc = 0; cc < 4; cc++) {
        {
            f32x4 acc1[3][4];
#pragma unroll
            for (int i = 0; i < 3; i++)
#pragma unroll
                for (int m = 0; m < 4; m++) acc1[i][m] = 0;
#pragma unroll
            for (int kk = 0; kk < 6; kk++) {
                bf16x8 a4[4];
#pragma unroll
                for (int mt = 0; mt < 4; mt++)
                    a4[mt] = *(const bf16x8*)&s_A[(mt*16 + ar)*LDA + kk*32 + ak];
#pragma unroll
                for (int ntl = 0; ntl < 3; ntl++) {
                    const int ngl = cc*192 + (wv*3 + ntl)*16 + ar;
                    bf16x8 w = *(const bf16x8*)&W1t[(size_t)ngl * 192 + kk*32 + ak];
#pragma unroll
                    for (int mt = 0; mt < 4; mt++)
                        acc1[ntl][mt] = MFMA(a4[mt], w, acc1[ntl][mt]);
                }
            }
#pragma unroll
            for (int ntl = 0; ntl < 3; ntl++) {
                const int ncol = (wv*3 + ntl)*16 + ar;
                const float bias = b1f[cc*192 + ncol];
#pragma unroll
                for (int mt = 0; mt < 4; mt++)
#pragma unroll
                    for (int rg = 0; rg < 4; rg++) {
                        const float z = acc1[ntl][mt][rg] + bias;
                        const float ge = 0.5f * z * (1.f + erff(z * 0.70710678118654752f));
                        s_H[(mt*16 + rg0 + rg)*LDA + ncol] = f2bf(ge);
                    }
            }
        }
        __syncthreads();
        {
#pragma unroll
            for (int kk = 0; kk < 6; kk++) {
                bf16x8 a4[4];
#pragma unroll
                for (int mt = 0; mt < 4; mt++)
                    a4[mt] = *(const bf16x8*)&s_H[(mt*16 + ar)*LDA + kk*32 + ak];
#pragma unroll
                for (int ntl = 0; ntl < 3; ntl++) {
                    const int col = (wv*3 + ntl)*16 + ar;
                    bf16x8 w = *(const bf16x8*)&W2t[(size_t)col * 768 + cc*192 + kk*32 + ak];
#pragma unroll
                    for (int mt = 0; mt < 4; mt++)
                        accO[ntl][mt] = MFMA(a4[mt], w, accO[ntl][mt]);
                }
            }
        }
        __syncthreads();
    }

#pragma unroll
    for (int ntl = 0; ntl < 3; ntl++) {
        const int col = (wv*3 + ntl)*16 + ar;
        const float bias = b2f[col];
#pragma unroll
        for (int mt = 0; mt < 4; mt++)
#pragma unroll
            for (int rg = 0; rg < 4; rg++) {
                const int row = mt*16 + rg0 + rg;
                if (row < NTOK) {
                    const int pi = row / 7, pj = row - pi * 7;
                    const int di = (wi * WSZ + pi + SSH) % HH;
                    const int dj = (wj * WSZ + pj + SSH) % HH;
                    out[((size_t)b * LTOT + di * HH + dj) * DIMC + col] =
                        accO[ntl][mt][rg] + bias + bf2f(s_XW[row*LDA + col]);
                }
            }
    }
}

extern "C" void kernel_launch(void* const* d_in, const int* in_sizes, int n_in,
                              void* d_out, int out_size, void* d_ws, size_t ws_size,
                              hipStream_t stream)
{
    const float* x      = (const float*)d_in[0];
    const float* qkv_w  = (const float*)d_in[1];
    const float* qkv_b  = (const float*)d_in[2];
    const float* proj_w = (const float*)d_in[3];
    const float* proj_b = (const float*)d_in[4];
    const float* g1     = (const float*)d_in[5];
    const float* be1    = (const float*)d_in[6];
    const float* g2     = (const float*)d_in[7];
    const float* be2    = (const float*)d_in[8];
    const float* w1     = (const float*)d_in[9];
    const float* b1     = (const float*)d_in[10];
    const float* w2     = (const float*)d_in[11];
    const float* b2     = (const float*)d_in[12];
    float* out = (float*)d_out;

    cvt_weights<<<256, 256, 0, stream>>>(qkv_w, proj_w, w1, w2, (u16*)d_ws);

    if (ws_size >= (size_t)WS_BYTES + XATTN_BYTES) {
        u16* xattn = (u16*)d_ws + WS_ELEMS;
        swin_attn<<<NWIN_T, 256, 0, stream>>>(x, qkv_b, proj_b, g1, be1,
                                              (const u16*)d_ws, xattn);
        swin_mlp<<<NTOKENS/64, 256, 0, stream>>>(xattn, g2, be2, b1, b2,
                                                 (const u16*)d_ws, out);
    } else {
        swin_mono<<<NWIN_T, 256, 0, stream>>>(x, qkv_b, proj_b, g1, be1, g2, be2,
                                              b1, b2, (const u16*)d_ws, out);
    }
}